// Round 3
// baseline (782.195 us; speedup 1.0000x reference)
//
#include <hip/hip_runtime.h>
#include <math.h>

#define TM 64
#define TN 64
#define TK 16

__device__ __forceinline__ float4 ld4(const float* p) {
    return *reinterpret_cast<const float4*>(p);
}

// C[M,N] = A[M,K] @ B' (+ C if ACC), B' = B[K,N] or (TRANSB) B[N,K]^T.
// A row-major lda=K, C row-major ldc=N. Batched via blockIdx.z with strides.
template<bool TRANSB, bool ACC>
__global__ __launch_bounds__(256)
void gemm_k(const float* __restrict__ A, long sA,
            const float* __restrict__ B, long sB,
            float* __restrict__ C, long sC,
            int M, int N, int K)
{
    __shared__ float As[TK][TM];
    __shared__ float Bs[TK][TN];
    const int z = blockIdx.z;
    A += (long)z * sA;  B += (long)z * sB;  C += (long)z * sC;
    const int m0 = blockIdx.x * TM;
    const int n0 = blockIdx.y * TN;
    const int tid = threadIdx.x;
    const int tx = tid & 15, ty = tid >> 4;

    // A (and transposed-B) load mapping: one float4 along K per thread
    const int ar = tid >> 2;            // 0..63 tile row
    const int ak = (tid & 3) << 2;      // k offset 0,4,8,12

    float acc[4][4] = {{0.f,0.f,0.f,0.f},{0.f,0.f,0.f,0.f},
                       {0.f,0.f,0.f,0.f},{0.f,0.f,0.f,0.f}};

    for (int k0 = 0; k0 < K; k0 += TK) {
        float4 av = make_float4(0.f,0.f,0.f,0.f);
        if (m0 + ar < M) av = ld4(A + (long)(m0 + ar) * K + (k0 + ak));
        // av components run along K -> store down the K axis (correct)
        As[ak+0][ar] = av.x; As[ak+1][ar] = av.y;
        As[ak+2][ar] = av.z; As[ak+3][ar] = av.w;

        if (TRANSB) {
            const int bn = tid >> 2;          // 0..63 tile col
            const int bk = (tid & 3) << 2;
            float4 bv = make_float4(0.f,0.f,0.f,0.f);
            if (n0 + bn < N) bv = ld4(B + (long)(n0 + bn) * K + (k0 + bk));
            // bv components run along K -> store down the K axis (correct)
            Bs[bk+0][bn] = bv.x; Bs[bk+1][bn] = bv.y;
            Bs[bk+2][bn] = bv.z; Bs[bk+3][bn] = bv.w;
        } else {
            const int bk = tid >> 4;          // 0..15
            const int bn = (tid & 15) << 2;   // 0..60
            // all non-trans uses have N multiple of 64 -> no guard needed
            float4 bv = ld4(B + (long)(k0 + bk) * N + (n0 + bn));
            // FIX (round-1 bug): bv components run along N -> store along N,
            // not down K. Previous code scattered them as Bs[bk+c][bn],
            // locally transposing every 4x4 sub-block of the B tile.
            Bs[bk][bn+0] = bv.x; Bs[bk][bn+1] = bv.y;
            Bs[bk][bn+2] = bv.z; Bs[bk][bn+3] = bv.w;
        }
        __syncthreads();

        #pragma unroll
        for (int kk = 0; kk < TK; ++kk) {
            float4 af = ld4(&As[kk][ty * 4]);
            float4 bf = ld4(&Bs[kk][tx * 4]);
            float a[4] = {af.x, af.y, af.z, af.w};
            float b[4] = {bf.x, bf.y, bf.z, bf.w};
            #pragma unroll
            for (int i = 0; i < 4; ++i)
                #pragma unroll
                for (int j = 0; j < 4; ++j)
                    acc[i][j] = fmaf(a[i], b[j], acc[i][j]);
        }
        __syncthreads();
    }

    #pragma unroll
    for (int i = 0; i < 4; ++i) {
        int row = m0 + ty * 4 + i;
        if (row >= M) continue;
        float* crow = C + (long)row * N;
        #pragma unroll
        for (int j = 0; j < 4; ++j) {
            int col = n0 + tx * 4 + j;
            if (col < N) {
                if (ACC) crow[col] += acc[i][j];
                else     crow[col]  = acc[i][j];
            }
        }
    }
}

// ---------------- softmax kernels ----------------
// one block (256 threads) per score row; NV = L/256 elements per thread

__device__ __forceinline__ float blockReduceMax(float v, float* red, int tid) {
    #pragma unroll
    for (int o = 32; o >= 1; o >>= 1) v = fmaxf(v, __shfl_xor(v, o));
    if ((tid & 63) == 0) red[tid >> 6] = v;
    __syncthreads();
    return fmaxf(fmaxf(red[0], red[1]), fmaxf(red[2], red[3]));
}

__device__ __forceinline__ float blockReduceSum(float v, float* red, int tid) {
    #pragma unroll
    for (int o = 32; o >= 1; o >>= 1) v += __shfl_xor(v, o);
    if ((tid & 63) == 0) red[4 + (tid >> 6)] = v;
    __syncthreads();
    return red[4] + red[5] + red[6] + red[7];
}

// H2H: e = (S + qe[b,i,mask]) * scale - 10000*(mask==0); row length 512
__global__ __launch_bounds__(256)
void softmax_h2h(float* __restrict__ S, const float* __restrict__ qe,
                 const int* __restrict__ mask, float scale)
{
    const int i = blockIdx.x, b = blockIdx.y;
    const long roff = (long)b * 512 + i;
    float* row = S + roff * 512;
    const int* mrow = mask + roff * 512;
    __shared__ float qsh[64];
    __shared__ float red[8];
    const int tid = threadIdx.x;
    if (tid < 64) qsh[tid] = qe[roff * 64 + tid];
    __syncthreads();

    float x[2];
    float mx = -1e30f;
    #pragma unroll
    for (int t = 0; t < 2; ++t) {
        int j = tid + t * 256;
        int m = mrow[j];
        float v = (row[j] + qsh[m]) * scale - 10000.f * (m == 0 ? 1.f : 0.f);
        x[t] = v; mx = fmaxf(mx, v);
    }
    mx = blockReduceMax(mx, red, tid);
    float s = 0.f;
    #pragma unroll
    for (int t = 0; t < 2; ++t) { x[t] = __expf(x[t] - mx); s += x[t]; }
    s = blockReduceSum(s, red, tid);
    float inv = 1.f / s;
    #pragma unroll
    for (int t = 0; t < 2; ++t) row[tid + t * 256] = x[t] * inv;
}

// T2T: e = (S + qp[b,i,clip(j-i)+6]) * scale - 10000*mask; row length 1024
__global__ __launch_bounds__(256)
void softmax_t2t(float* __restrict__ S, const float* __restrict__ qp,
                 const float* __restrict__ mask, float scale)
{
    const int i = blockIdx.x, b = blockIdx.y;
    const long roff = (long)b * 1024 + i;
    float* row = S + roff * 1024;
    const float* mrow = mask + roff * 1024;
    __shared__ float qsh[13];
    __shared__ float red[8];
    const int tid = threadIdx.x;
    if (tid < 13) qsh[tid] = qp[roff * 13 + tid];
    __syncthreads();

    float x[4];
    float mx = -1e30f;
    #pragma unroll
    for (int t = 0; t < 4; ++t) {
        int j = tid + t * 256;
        int pos = j - i;
        pos = (pos < -6 ? -6 : (pos > 6 ? 6 : pos)) + 6;
        float v = (row[j] + qsh[pos]) * scale - 10000.f * mrow[j];
        x[t] = v; mx = fmaxf(mx, v);
    }
    mx = blockReduceMax(mx, red, tid);
    float s = 0.f;
    #pragma unroll
    for (int t = 0; t < 4; ++t) { x[t] = __expf(x[t] - mx); s += x[t]; }
    s = blockReduceSum(s, red, tid);
    float inv = 1.f / s;
    #pragma unroll
    for (int t = 0; t < 4; ++t) row[tid + t * 256] = x[t] * inv;
}

// H2T (mask) / T2H (no mask): e = S*scale [- 10000*mask]
template<int L, bool HASMASK>
__global__ __launch_bounds__(256)
void softmax_plain(float* __restrict__ S, const float* __restrict__ mask,
                   float scale)
{
    const int i = blockIdx.x, b = blockIdx.y;
    const long roff = ((long)b * gridDim.x + i) * L;
    float* row = S + roff;
    const float* mrow = HASMASK ? (mask + roff) : nullptr;
    __shared__ float red[8];
    const int tid = threadIdx.x;
    constexpr int NV = L / 256;

    float x[NV];
    float mx = -1e30f;
    #pragma unroll
    for (int t = 0; t < NV; ++t) {
        int j = tid + t * 256;
        float v = row[j] * scale;
        if (HASMASK) v -= 10000.f * mrow[j];
        x[t] = v; mx = fmaxf(mx, v);
    }
    mx = blockReduceMax(mx, red, tid);
    float s = 0.f;
    #pragma unroll
    for (int t = 0; t < NV; ++t) { x[t] = __expf(x[t] - mx); s += x[t]; }
    s = blockReduceSum(s, red, tid);
    float inv = 1.f / s;
    #pragma unroll
    for (int t = 0; t < NV; ++t) row[tid + t * 256] = x[t] * inv;
}

// ---------------- host side ----------------

static void launch_gemm(bool transb, bool acc,
                        const float* A, long sA, const float* B, long sB,
                        float* C, long sC, int M, int N, int K, int batch,
                        hipStream_t stream)
{
    dim3 grid((M + TM - 1) / TM, (N + TN - 1) / TN, batch);
    dim3 block(256);
    if (transb) {
        if (acc) gemm_k<true, true><<<grid, block, 0, stream>>>(A, sA, B, sB, C, sC, M, N, K);
        else     gemm_k<true, false><<<grid, block, 0, stream>>>(A, sA, B, sB, C, sC, M, N, K);
    } else {
        if (acc) gemm_k<false, true><<<grid, block, 0, stream>>>(A, sA, B, sB, C, sC, M, N, K);
        else     gemm_k<false, false><<<grid, block, 0, stream>>>(A, sA, B, sB, C, sC, M, N, K);
    }
}

extern "C" void kernel_launch(void* const* d_in, const int* in_sizes, int n_in,
                              void* d_out, int out_size, void* d_ws, size_t ws_size,
                              hipStream_t stream)
{
    const int B = 4, Lt = 1024, Lh = 512, Dd = 384;
    const float scale = 0.05103103630798288f;  // 1/sqrt(384)

    const float* text     = (const float*)d_in[0];
    const float* html     = (const float*)d_in[1];
    const int*   H2Hmask  = (const int*)  d_in[2];
    const float* T2Tmask  = (const float*)d_in[3];
    const float* H2Tmask  = (const float*)d_in[4];
    // d_in[5] (T2Hmask) unused by reference
    const float* posemb   = (const float*)d_in[6];
    const float* edgeemb  = (const float*)d_in[7];
    const float* W_V_T    = (const float*)d_in[8];
    const float* W_V_H    = (const float*)d_in[9];
    const float* W_Q_H2H  = (const float*)d_in[10];
    const float* W_K_H2H  = (const float*)d_in[11];
    const float* W_Q_H2T  = (const float*)d_in[12];
    const float* W_K_H2T  = (const float*)d_in[13];
    const float* W_Q_T2H  = (const float*)d_in[14];
    const float* W_K_T2H  = (const float*)d_in[15];
    const float* W_Q_T2T  = (const float*)d_in[16];
    const float* W_K_T2T  = (const float*)d_in[17];

    float* out = (float*)d_out;

    // workspace carve
    float* ws = (float*)d_ws;
    const long szT = (long)B * Lt * Dd;  // 1572864
    const long szH = (long)B * Lh * Dd;  // 786432
    float* text_v = ws; ws += szT;
    float* html_v = ws; ws += szH;
    float* h2h_q  = ws; ws += szH;
    float* h2h_k  = ws; ws += szH;
    float* h2t_q  = ws; ws += szH;
    float* h2t_k  = ws; ws += szT;
    float* t2h_q  = ws; ws += szT;
    float* t2h_k  = ws; ws += szH;
    float* t2t_q  = ws; ws += szT;
    float* t2t_k  = ws; ws += szT;
    float* qe     = ws; ws += (long)B * Lh * 64;
    float* qp     = ws; ws += (long)B * Lt * 13;
    float* scores = ws;                        // up to B*Lt*Lt floats

    // ---- projections (batch=1, M = B*L) ----
    launch_gemm(false, false, text, 0, W_V_T,   0, text_v, 0, B*Lt, Dd, Dd, 1, stream);
    launch_gemm(false, false, html, 0, W_V_H,   0, html_v, 0, B*Lh, Dd, Dd, 1, stream);
    launch_gemm(false, false, html, 0, W_Q_H2H, 0, h2h_q,  0, B*Lh, Dd, Dd, 1, stream);
    launch_gemm(false, false, html, 0, W_K_H2H, 0, h2h_k,  0, B*Lh, Dd, Dd, 1, stream);
    launch_gemm(false, false, html, 0, W_Q_H2T, 0, h2t_q,  0, B*Lh, Dd, Dd, 1, stream);
    launch_gemm(false, false, text, 0, W_K_H2T, 0, h2t_k,  0, B*Lt, Dd, Dd, 1, stream);
    launch_gemm(false, false, text, 0, W_Q_T2H, 0, t2h_q,  0, B*Lt, Dd, Dd, 1, stream);
    launch_gemm(false, false, html, 0, W_K_T2H, 0, t2h_k,  0, B*Lh, Dd, Dd, 1, stream);
    launch_gemm(false, false, text, 0, W_Q_T2T, 0, t2t_q,  0, B*Lt, Dd, Dd, 1, stream);
    launch_gemm(false, false, text, 0, W_K_T2T, 0, t2t_k,  0, B*Lt, Dd, Dd, 1, stream);

    // ---- small gathers' GEMMs: qe = h2h_q @ edge^T, qp = t2t_q @ pos^T ----
    launch_gemm(true, false, h2h_q, 0, edgeemb, 0, qe, 0, B*Lh, 64, Dd, 1, stream);
    launch_gemm(true, false, t2t_q, 0, posemb,  0, qp, 0, B*Lt, 13, Dd, 1, stream);

    const long sQt = (long)Lt * Dd, sQh = (long)Lh * Dd;
    const long sOut = (long)(Lt + Lh) * Dd;

    // ---- H2H ----
    launch_gemm(true, false, h2h_q, sQh, h2h_k, sQh, scores, (long)Lh*Lh,
                Lh, Lh, Dd, B, stream);
    softmax_h2h<<<dim3(Lh, B), 256, 0, stream>>>(scores, qe, H2Hmask, scale);
    launch_gemm(false, false, scores, (long)Lh*Lh, html_v, sQh,
                out + (long)Lt * Dd, sOut, Lh, Dd, Lh, B, stream);   // html1

    // ---- H2T ----
    launch_gemm(true, false, h2t_q, sQh, h2t_k, sQt, scores, (long)Lh*Lt,
                Lh, Lt, Dd, B, stream);
    softmax_plain<1024, true><<<dim3(Lh, B), 256, 0, stream>>>(scores, H2Tmask, scale);
    launch_gemm(false, true, scores, (long)Lh*Lt, text_v, sQt,
                out + (long)Lt * Dd, sOut, Lh, Dd, Lt, B, stream);   // html2 (+=)

    // ---- T2H ----
    launch_gemm(true, false, t2h_q, sQt, t2h_k, sQh, scores, (long)Lt*Lh,
                Lt, Lh, Dd, B, stream);
    softmax_plain<512, false><<<dim3(Lt, B), 256, 0, stream>>>(scores, nullptr, scale);
    launch_gemm(false, false, scores, (long)Lt*Lh, html_v, sQh,
                out, sOut, Lt, Dd, Lh, B, stream);                   // text1

    // ---- T2T ----
    launch_gemm(true, false, t2t_q, sQt, t2t_k, sQt, scores, (long)Lt*Lt,
                Lt, Lt, Dd, B, stream);
    softmax_t2t<<<dim3(Lt, B), 256, 0, stream>>>(scores, qp, T2Tmask, scale);
    launch_gemm(false, true, scores, (long)Lt*Lt, text_v, sQt,
                out, sOut, Lt, Dd, Lt, B, stream);                   // text2 (+=)
}

// Round 4
// 430.616 us; speedup vs baseline: 1.8165x; 1.8165x over previous
//
#include <hip/hip_runtime.h>
#include <math.h>

typedef unsigned short u16;
typedef unsigned int u32;
typedef __attribute__((ext_vector_type(8))) short short8;
typedef __attribute__((ext_vector_type(4))) float f32x4;

__device__ __forceinline__ u16 f2bf(float f) {
    u32 u = __float_as_uint(f);
    u = (u + 0x7FFFu + ((u >> 16) & 1u)) >> 16;   // RNE
    return (u16)u;
}
__device__ __forceinline__ float bf2f(u16 h) {
    return __uint_as_float(((u32)h) << 16);
}
__device__ __forceinline__ float4 ld4f(const float* p) {
    return *reinterpret_cast<const float4*>(p);
}

// ============ conversion kernels ============

// fp32 -> bf16 for text and html (element counts multiples of 4)
__global__ __launch_bounds__(256)
void cvt2(const float4* __restrict__ a, int na4,
          const float4* __restrict__ b, int nb4,
          u16* __restrict__ oa, u16* __restrict__ ob)
{
    int idx = blockIdx.x * 256 + threadIdx.x;
    const int tot = na4 + nb4;
    for (; idx < tot; idx += gridDim.x * 256) {
        float4 v; u16* o;
        if (idx < na4) { v = a[idx];        o = oa + (long)idx * 4; }
        else           { v = b[idx - na4];  o = ob + (long)(idx - na4) * 4; }
        u32 lo = (u32)f2bf(v.x) | ((u32)f2bf(v.y) << 16);
        u32 hi = (u32)f2bf(v.z) | ((u32)f2bf(v.w) << 16);
        uint2 pk; pk.x = lo; pk.y = hi;
        *reinterpret_cast<uint2*>(o) = pk;
    }
}

struct WP { const float* p[10]; };

// W [384][384] fp32 -> W^T [384][384] bf16, 10 weights via blockIdx.z
__global__ __launch_bounds__(1024)
void wtrans(WP w, u16* __restrict__ out)
{
    __shared__ float t[32][33];
    const int z = blockIdx.z;
    const float* W = w.p[z];
    const int k = blockIdx.x * 32 + threadIdx.y;   // row of W
    const int n = blockIdx.y * 32 + threadIdx.x;   // col of W
    t[threadIdx.y][threadIdx.x] = W[k * 384 + n];
    __syncthreads();
    const int no = blockIdx.y * 32 + threadIdx.y;
    const int ko = blockIdx.x * 32 + threadIdx.x;
    out[(long)z * 147456 + no * 384 + ko] = f2bf(t[threadIdx.x][threadIdx.y]);
}

// ============ MFMA NT GEMM ============
// C[M,N](+)= A[M,K] . B[N,K]^T  (both bf16, K-contiguous rows), fp32 accum.
// MODE: 0 = write f32, 1 = accumulate f32, 2 = write bf16,
//       3 = write bf16 TRANSPOSED into VT[B][384][ldc] (ldc = L, batch from row/ldc)
// Tile 128x128, 4 waves (2x2 of 64x64), BK=32, mfma_f32_16x16x32_bf16.
// Requires M%128==0, N%128==0, K%32==0 (all call sites satisfy this).
template<int MODE>
__global__ __launch_bounds__(256)
void gemm_mfma(const u16* __restrict__ A, long sA,
               const u16* __restrict__ B, long sB,
               void* __restrict__ Cv, long sC,
               int K, int ldc)
{
    __shared__ u16 As[128 * 32];
    __shared__ u16 Bs[128 * 32];

    const int z  = blockIdx.z;
    const int m0 = blockIdx.x * 128;
    const int n0 = blockIdx.y * 128;
    A += (long)z * sA + (long)m0 * K;
    B += (long)z * sB + (long)n0 * K;

    const int tid  = threadIdx.x;
    const int wid  = tid >> 6;
    const int lane = tid & 63;
    const int wr = wid >> 1, wc = wid & 1;
    const int lane15 = lane & 15;
    const int kg = (lane >> 4) * 8;          // k offset of this lane's fragment
    const int srow = lane >> 2;              // staging: row within 16-row group
    const int scol = (lane & 3) * 8;         // staging: element col (8 bf16 = 16B)

    f32x4 acc[4][4];
    #pragma unroll
    for (int i = 0; i < 4; ++i)
        #pragma unroll
        for (int j = 0; j < 4; ++j)
            acc[i][j] = (f32x4){0.f, 0.f, 0.f, 0.f};

    for (int k0 = 0; k0 < K; k0 += 32) {
        // stage 8KB A-tile + 8KB B-tile: per wave 2 issues each, 1024B/issue.
        // LDS layout row-major [128][32] bf16 (64B rows) -> linear dest, so
        // global src addr = row-major tile walk (guide §5 global_load_lds rules).
        #pragma unroll
        for (int i = 0; i < 2; ++i) {
            const int rg = (wid * 2 + i) * 16;
            const u16* ga = A + (long)(rg + srow) * K + (k0 + scol);
            const u16* gb = B + (long)(rg + srow) * K + (k0 + scol);
            u16* la = As + (wid * 2 + i) * 512;   // wave-uniform base
            u16* lb = Bs + (wid * 2 + i) * 512;
            __builtin_amdgcn_global_load_lds(
                (const __attribute__((address_space(1))) void*)ga,
                (__attribute__((address_space(3))) void*)la, 16, 0, 0);
            __builtin_amdgcn_global_load_lds(
                (const __attribute__((address_space(1))) void*)gb,
                (__attribute__((address_space(3))) void*)lb, 16, 0, 0);
        }
        __syncthreads();   // drains vmcnt -> tiles visible

        short8 af[4], bf[4];
        #pragma unroll
        for (int mi = 0; mi < 4; ++mi)
            af[mi] = *reinterpret_cast<const short8*>(
                As + (wr * 64 + mi * 16 + lane15) * 32 + kg);
        #pragma unroll
        for (int ni = 0; ni < 4; ++ni)
            bf[ni] = *reinterpret_cast<const short8*>(
                Bs + (wc * 64 + ni * 16 + lane15) * 32 + kg);
        #pragma unroll
        for (int mi = 0; mi < 4; ++mi)
            #pragma unroll
            for (int ni = 0; ni < 4; ++ni)
                acc[mi][ni] = __builtin_amdgcn_mfma_f32_16x16x32_bf16(
                    af[mi], bf[ni], acc[mi][ni], 0, 0, 0);
        __syncthreads();   // LDS reuse next iteration
    }

    // epilogue. C/D frag: col = lane&15, row = (lane>>4)*4 + reg  [m89]
    const int r0 = (lane >> 4) * 4;
    if (MODE == 0 || MODE == 1) {
        float* C = (float*)Cv + (long)z * sC;
        #pragma unroll
        for (int mi = 0; mi < 4; ++mi)
            #pragma unroll
            for (int r = 0; r < 4; ++r) {
                const int row = m0 + wr * 64 + mi * 16 + r0 + r;
                float* crow = C + (long)row * ldc + n0 + wc * 64 + lane15;
                #pragma unroll
                for (int ni = 0; ni < 4; ++ni) {
                    if (MODE == 1) crow[ni * 16] += acc[mi][ni][r];
                    else           crow[ni * 16]  = acc[mi][ni][r];
                }
            }
    } else if (MODE == 2) {
        u16* C = (u16*)Cv + (long)z * sC;
        #pragma unroll
        for (int mi = 0; mi < 4; ++mi)
            #pragma unroll
            for (int r = 0; r < 4; ++r) {
                const int row = m0 + wr * 64 + mi * 16 + r0 + r;
                u16* crow = C + (long)row * ldc + n0 + wc * 64 + lane15;
                #pragma unroll
                for (int ni = 0; ni < 4; ++ni)
                    crow[ni * 16] = f2bf(acc[mi][ni][r]);
            }
    } else {
        // transposed: out[b][col][l], b = row/ldc, l = row%ldc; 4 regs = 4
        // consecutive l -> one 8B store.
        u16* C = (u16*)Cv;
        #pragma unroll
        for (int mi = 0; mi < 4; ++mi) {
            const int row = m0 + wr * 64 + mi * 16 + r0;
            const int bz = row / ldc;
            const int l  = row % ldc;
            #pragma unroll
            for (int ni = 0; ni < 4; ++ni) {
                const int col = n0 + wc * 64 + ni * 16 + lane15;
                u32 lo = (u32)f2bf(acc[mi][ni][0]) | ((u32)f2bf(acc[mi][ni][1]) << 16);
                u32 hi = (u32)f2bf(acc[mi][ni][2]) | ((u32)f2bf(acc[mi][ni][3]) << 16);
                uint2 pk; pk.x = lo; pk.y = hi;
                *reinterpret_cast<uint2*>(C + ((long)bz * 384 + col) * ldc + l) = pk;
            }
        }
    }
}

// ============ small fp32-accum GEMM for qe/qp bias tables ============
// C[M,N] = A[M,K](bf16) . B[N,K](f32)^T ; 64x64 tile, guards on N only.
__global__ __launch_bounds__(256)
void gemm_bias(const u16* __restrict__ A, const float* __restrict__ B,
               float* __restrict__ C, int M, int N, int K)
{
    __shared__ float As[16][64];
    __shared__ float Bs[16][64];
    const int m0 = blockIdx.x * 64;
    const int n0 = blockIdx.y * 64;
    const int tid = threadIdx.x;
    const int tx = tid & 15, ty = tid >> 4;
    const int ar = tid >> 2;
    const int ak = (tid & 3) << 2;

    float acc[4][4] = {{0.f,0.f,0.f,0.f},{0.f,0.f,0.f,0.f},
                       {0.f,0.f,0.f,0.f},{0.f,0.f,0.f,0.f}};

    for (int k0 = 0; k0 < K; k0 += 16) {
        const u16* ap = A + (long)(m0 + ar) * K + (k0 + ak);
        ushort4 a4 = *reinterpret_cast<const ushort4*>(ap);
        As[ak+0][ar] = bf2f(a4.x); As[ak+1][ar] = bf2f(a4.y);
        As[ak+2][ar] = bf2f(a4.z); As[ak+3][ar] = bf2f(a4.w);

        float4 bv = make_float4(0.f,0.f,0.f,0.f);
        if (n0 + ar < N) bv = ld4f(B + (long)(n0 + ar) * K + (k0 + ak));
        Bs[ak+0][ar] = bv.x; Bs[ak+1][ar] = bv.y;
        Bs[ak+2][ar] = bv.z; Bs[ak+3][ar] = bv.w;
        __syncthreads();

        #pragma unroll
        for (int kk = 0; kk < 16; ++kk) {
            float4 af = ld4f(&As[kk][ty * 4]);
            float4 bfv = ld4f(&Bs[kk][tx * 4]);
            float a[4] = {af.x, af.y, af.z, af.w};
            float b[4] = {bfv.x, bfv.y, bfv.z, bfv.w};
            #pragma unroll
            for (int i = 0; i < 4; ++i)
                #pragma unroll
                for (int j = 0; j < 4; ++j)
                    acc[i][j] = fmaf(a[i], b[j], acc[i][j]);
        }
        __syncthreads();
    }
    #pragma unroll
    for (int i = 0; i < 4; ++i) {
        const int row = m0 + ty * 4 + i;
        float* crow = C + (long)row * N;
        #pragma unroll
        for (int j = 0; j < 4; ++j) {
            const int col = n0 + tx * 4 + j;
            if (col < N) crow[col] = acc[i][j];
        }
    }
}

// ============ softmax kernels (fp32 in, bf16 probs out) ============

__device__ __forceinline__ float blockReduceMax(float v, float* red, int tid) {
    #pragma unroll
    for (int o = 32; o >= 1; o >>= 1) v = fmaxf(v, __shfl_xor(v, o));
    if ((tid & 63) == 0) red[tid >> 6] = v;
    __syncthreads();
    return fmaxf(fmaxf(red[0], red[1]), fmaxf(red[2], red[3]));
}
__device__ __forceinline__ float blockReduceSum(float v, float* red, int tid) {
    #pragma unroll
    for (int o = 32; o >= 1; o >>= 1) v += __shfl_xor(v, o);
    if ((tid & 63) == 0) red[4 + (tid >> 6)] = v;
    __syncthreads();
    return red[4] + red[5] + red[6] + red[7];
}

__global__ __launch_bounds__(256)
void softmax_h2h(const float* __restrict__ S, u16* __restrict__ P,
                 const float* __restrict__ qe, const int* __restrict__ mask,
                 float scale)
{
    const int i = blockIdx.x, b = blockIdx.y;
    const long roff = (long)b * 512 + i;
    const float* row = S + roff * 512;
    u16* prow = P + roff * 512;
    const int* mrow = mask + roff * 512;
    __shared__ float qsh[64];
    __shared__ float red[8];
    const int tid = threadIdx.x;
    if (tid < 64) qsh[tid] = qe[roff * 64 + tid];
    __syncthreads();

    float x[2]; float mx = -1e30f;
    #pragma unroll
    for (int t = 0; t < 2; ++t) {
        const int j = tid + t * 256;
        const int m = mrow[j];
        float v = (row[j] + qsh[m]) * scale - 10000.f * (m == 0 ? 1.f : 0.f);
        x[t] = v; mx = fmaxf(mx, v);
    }
    mx = blockReduceMax(mx, red, tid);
    float s = 0.f;
    #pragma unroll
    for (int t = 0; t < 2; ++t) { x[t] = __expf(x[t] - mx); s += x[t]; }
    s = blockReduceSum(s, red, tid);
    const float inv = 1.f / s;
    #pragma unroll
    for (int t = 0; t < 2; ++t) prow[tid + t * 256] = f2bf(x[t] * inv);
}

__global__ __launch_bounds__(256)
void softmax_t2t(const float* __restrict__ S, u16* __restrict__ P,
                 const float* __restrict__ qp, const float* __restrict__ mask,
                 float scale)
{
    const int i = blockIdx.x, b = blockIdx.y;
    const long roff = (long)b * 1024 + i;
    const float* row = S + roff * 1024;
    u16* prow = P + roff * 1024;
    const float* mrow = mask + roff * 1024;
    __shared__ float qsh[13];
    __shared__ float red[8];
    const int tid = threadIdx.x;
    if (tid < 13) qsh[tid] = qp[roff * 13 + tid];
    __syncthreads();

    float x[4]; float mx = -1e30f;
    #pragma unroll
    for (int t = 0; t < 4; ++t) {
        const int j = tid + t * 256;
        int pos = j - i;
        pos = (pos < -6 ? -6 : (pos > 6 ? 6 : pos)) + 6;
        float v = (row[j] + qsh[pos]) * scale - 10000.f * mrow[j];
        x[t] = v; mx = fmaxf(mx, v);
    }
    mx = blockReduceMax(mx, red, tid);
    float s = 0.f;
    #pragma unroll
    for (int t = 0; t < 4; ++t) { x[t] = __expf(x[t] - mx); s += x[t]; }
    s = blockReduceSum(s, red, tid);
    const float inv = 1.f / s;
    #pragma unroll
    for (int t = 0; t < 4; ++t) prow[tid + t * 256] = f2bf(x[t] * inv);
}

template<int L, bool HASMASK>
__global__ __launch_bounds__(256)
void softmax_plain(const float* __restrict__ S, u16* __restrict__ P,
                   const float* __restrict__ mask, float scale)
{
    const int i = blockIdx.x, b = blockIdx.y;
    const long roff = ((long)b * gridDim.x + i) * L;
    const float* row = S + roff;
    u16* prow = P + roff;
    const float* mrow = HASMASK ? (mask + roff) : nullptr;
    __shared__ float red[8];
    const int tid = threadIdx.x;
    constexpr int NV = L / 256;

    float x[NV]; float mx = -1e30f;
    #pragma unroll
    for (int t = 0; t < NV; ++t) {
        const int j = tid + t * 256;
        float v = row[j] * scale;
        if (HASMASK) v -= 10000.f * mrow[j];
        x[t] = v; mx = fmaxf(mx, v);
    }
    mx = blockReduceMax(mx, red, tid);
    float s = 0.f;
    #pragma unroll
    for (int t = 0; t < NV; ++t) { x[t] = __expf(x[t] - mx); s += x[t]; }
    s = blockReduceSum(s, red, tid);
    const float inv = 1.f / s;
    #pragma unroll
    for (int t = 0; t < NV; ++t) prow[tid + t * 256] = f2bf(x[t] * inv);
}

// ============ host side ============

extern "C" void kernel_launch(void* const* d_in, const int* in_sizes, int n_in,
                              void* d_out, int out_size, void* d_ws, size_t ws_size,
                              hipStream_t stream)
{
    const int Bn = 4, Lt = 1024, Lh = 512, Dd = 384;
    const float scale = 0.05103103630798288f;  // 1/sqrt(384)

    const float* text    = (const float*)d_in[0];
    const float* html    = (const float*)d_in[1];
    const int*   H2Hmask = (const int*)  d_in[2];
    const float* T2Tmask = (const float*)d_in[3];
    const float* H2Tmask = (const float*)d_in[4];
    const float* posemb  = (const float*)d_in[6];
    const float* edgeemb = (const float*)d_in[7];
    float* out = (float*)d_out;

    // ---- workspace carve (all 256B-aligned) ----
    char* p = (char*)d_ws;
    auto au16 = [&](long n) { u16* r = (u16*)p;  p += ((n * 2 + 255) & ~255L); return r; };
    auto af32 = [&](long n) { float* r = (float*)p; p += ((n * 4 + 255) & ~255L); return r; };

    const long nT = (long)Bn * Lt * Dd;   // 1572864
    const long nH = (long)Bn * Lh * Dd;   //  786432
    u16* text_bf = au16(nT);
    u16* html_bf = au16(nH);
    u16* WT      = au16(10L * 384 * 384);
    u16* h2h_q = au16(nH);
    u16* h2h_k = au16(nH);
    u16* h2t_q = au16(nH);
    u16* h2t_k = au16(nT);
    u16* t2h_q = au16(nT);
    u16* t2h_k = au16(nH);
    u16* t2t_q = au16(nT);
    u16* t2t_k = au16(nT);
    u16* text_vT = au16(nT);              // [B][384][Lt]
    u16* html_vT = au16(nH);              // [B][384][Lh]
    float* qe = af32((long)Bn * Lh * 64);
    float* qp = af32((long)Bn * Lt * 13);
    float* scores = af32((long)Bn * Lt * Lt);
    u16*   probs  = au16((long)Bn * Lt * Lt);

    // ---- conversions ----
    cvt2<<<2048, 256, 0, stream>>>((const float4*)text, (int)(nT / 4),
                                   (const float4*)html, (int)(nH / 4),
                                   text_bf, html_bf);
    WP wp;
    for (int i = 0; i < 10; ++i) wp.p[i] = (const float*)d_in[8 + i];
    wtrans<<<dim3(12, 12, 10), dim3(32, 32), 0, stream>>>(wp, WT);

    auto mfma = [&](int mode, const u16* A, long sA, const u16* B, long sB,
                    void* C, long sC, int M, int N, int K, int ldc, int batch) {
        dim3 g(M / 128, N / 128, batch), blk(256);
        switch (mode) {
        case 0: gemm_mfma<0><<<g, blk, 0, stream>>>(A, sA, B, sB, C, sC, K, ldc); break;
        case 1: gemm_mfma<1><<<g, blk, 0, stream>>>(A, sA, B, sB, C, sC, K, ldc); break;
        case 2: gemm_mfma<2><<<g, blk, 0, stream>>>(A, sA, B, sB, C, sC, K, ldc); break;
        default: gemm_mfma<3><<<g, blk, 0, stream>>>(A, sA, B, sB, C, sC, K, ldc); break;
        }
    };
    auto WTi = [&](int i) { return WT + (long)i * 147456; };

    // ---- projections (batch=1, flattened M) ----
    // d_in order: 8 W_V_T, 9 W_V_H, 10 W_Q_H2H, 11 W_K_H2H, 12 W_Q_H2T,
    //             13 W_K_H2T, 14 W_Q_T2H, 15 W_K_T2H, 16 W_Q_T2T, 17 W_K_T2T
    mfma(3, text_bf, 0, WTi(0), 0, text_vT, 0, Bn * Lt, Dd, Dd, Lt, 1); // V_T -> [B][D][Lt]
    mfma(3, html_bf, 0, WTi(1), 0, html_vT, 0, Bn * Lh, Dd, Dd, Lh, 1); // V_H -> [B][D][Lh]
    mfma(2, html_bf, 0, WTi(2), 0, h2h_q, 0, Bn * Lh, Dd, Dd, Dd, 1);
    mfma(2, html_bf, 0, WTi(3), 0, h2h_k, 0, Bn * Lh, Dd, Dd, Dd, 1);
    mfma(2, html_bf, 0, WTi(4), 0, h2t_q, 0, Bn * Lh, Dd, Dd, Dd, 1);
    mfma(2, text_bf, 0, WTi(5), 0, h2t_k, 0, Bn * Lt, Dd, Dd, Dd, 1);
    mfma(2, text_bf, 0, WTi(6), 0, t2h_q, 0, Bn * Lt, Dd, Dd, Dd, 1);
    mfma(2, html_bf, 0, WTi(7), 0, t2h_k, 0, Bn * Lh, Dd, Dd, Dd, 1);
    mfma(2, text_bf, 0, WTi(8), 0, t2t_q, 0, Bn * Lt, Dd, Dd, Dd, 1);
    mfma(2, text_bf, 0, WTi(9), 0, t2t_k, 0, Bn * Lt, Dd, Dd, Dd, 1);

    // ---- bias tables (fp32-accum path, fp32 embeddings) ----
    gemm_bias<<<dim3((Bn * Lh) / 64, 1), 256, 0, stream>>>(h2h_q, edgeemb, qe, Bn * Lh, 64, Dd);
    gemm_bias<<<dim3((Bn * Lt) / 64, 1), 256, 0, stream>>>(t2t_q, posemb,  qp, Bn * Lt, 13, Dd);

    const long sQt = (long)Lt * Dd, sQh = (long)Lh * Dd;
    const long sVt = (long)Dd * Lt, sVh = (long)Dd * Lh;
    const long sOut = (long)(Lt + Lh) * Dd;
    float* outH = out + (long)Lt * Dd;

    // ---- H2H ----
    mfma(0, h2h_q, sQh, h2h_k, sQh, scores, (long)Lh * Lh, Lh, Lh, Dd, Lh, Bn);
    softmax_h2h<<<dim3(Lh, Bn), 256, 0, stream>>>(scores, probs, qe, H2Hmask, scale);
    mfma(0, probs, (long)Lh * Lh, html_vT, sVh, outH, sOut, Lh, Dd, Lh, Dd, Bn);

    // ---- H2T ----
    mfma(0, h2t_q, sQh, h2t_k, sQt, scores, (long)Lh * Lt, Lh, Lt, Dd, Lt, Bn);
    softmax_plain<1024, true><<<dim3(Lh, Bn), 256, 0, stream>>>(scores, probs, H2Tmask, scale);
    mfma(1, probs, (long)Lh * Lt, text_vT, sVt, outH, sOut, Lh, Dd, Lt, Dd, Bn);

    // ---- T2H ----
    mfma(0, t2h_q, sQt, t2h_k, sQh, scores, (long)Lt * Lh, Lt, Lh, Dd, Lh, Bn);
    softmax_plain<512, false><<<dim3(Lt, Bn), 256, 0, stream>>>(scores, probs, nullptr, scale);
    mfma(0, probs, (long)Lt * Lh, html_vT, sVh, out, sOut, Lt, Dd, Lh, Dd, Bn);

    // ---- T2T ----
    mfma(0, t2t_q, sQt, t2t_k, sQt, scores, (long)Lt * Lt, Lt, Lt, Dd, Lt, Bn);
    softmax_t2t<<<dim3(Lt, Bn), 256, 0, stream>>>(scores, probs, qp, T2Tmask, scale);
    mfma(1, probs, (long)Lt * Lt, text_vT, sVt, out, sOut, Lt, Dd, Lt, Dd, Bn);
}

// Round 5
// 282.153 us; speedup vs baseline: 2.7722x; 1.5262x over previous
//
#include <hip/hip_runtime.h>
#include <math.h>

typedef unsigned short u16;
typedef unsigned int u32;
typedef __attribute__((ext_vector_type(8))) short short8;
typedef __attribute__((ext_vector_type(4))) float f32x4;

__device__ __forceinline__ u16 f2bf(float f) {
    u32 u = __float_as_uint(f);
    u = (u + 0x7FFFu + ((u >> 16) & 1u)) >> 16;   // RNE
    return (u16)u;
}
__device__ __forceinline__ float bf2f(u16 h) {
    return __uint_as_float(((u32)h) << 16);
}
__device__ __forceinline__ float4 ld4f(const float* p) {
    return *reinterpret_cast<const float4*>(p);
}

// ============ conversion kernels ============

__global__ __launch_bounds__(256)
void cvt2(const float4* __restrict__ a, int na4,
          const float4* __restrict__ b, int nb4,
          u16* __restrict__ oa, u16* __restrict__ ob)
{
    int idx = blockIdx.x * 256 + threadIdx.x;
    const int tot = na4 + nb4;
    for (; idx < tot; idx += gridDim.x * 256) {
        float4 v; u16* o;
        if (idx < na4) { v = a[idx];        o = oa + (long)idx * 4; }
        else           { v = b[idx - na4];  o = ob + (long)(idx - na4) * 4; }
        u32 lo = (u32)f2bf(v.x) | ((u32)f2bf(v.y) << 16);
        u32 hi = (u32)f2bf(v.z) | ((u32)f2bf(v.w) << 16);
        uint2 pk; pk.x = lo; pk.y = hi;
        *reinterpret_cast<uint2*>(o) = pk;
    }
}

struct WP { const float* p[10]; };
struct WD { u16* d[10]; };

// W [384][384] fp32 -> W^T bf16 at per-weight destination
__global__ __launch_bounds__(1024)
void wtrans(WP w, WD wd)
{
    __shared__ float t[32][33];
    const int z = blockIdx.z;
    const float* W = w.p[z];
    const int k = blockIdx.x * 32 + threadIdx.y;   // row of W
    const int n = blockIdx.y * 32 + threadIdx.x;   // col of W
    t[threadIdx.y][threadIdx.x] = W[k * 384 + n];
    __syncthreads();
    const int no = blockIdx.y * 32 + threadIdx.y;
    const int ko = blockIdx.x * 32 + threadIdx.x;
    wd.d[z][no * 384 + ko] = f2bf(t[threadIdx.x][threadIdx.y]);
}

// ============ 64x64 MFMA NT GEMM, double-buffered, LDS-swizzled ============
// C[M,N](+)= A[M,K] . B[N,K]^T (bf16, rows lda/ldb-strided, K-contiguous).
// Tile 64x64, 4 waves (2x2 of 32x32), BK=64, mfma_f32_16x16x32_bf16.
// LDS tile [64 rows][8 granules of 16B]; granule (row,s) holds global
// colslot s ^ (row&7)  ->  read (row,c) at granule c ^ (row&7). The
// global SOURCE is pre-swizzled so global_load_lds can write linearly
// (rule: swizzle both sides or neither).
// MODE: 0 = f32 write, 1 = f32 accumulate,
//       4 = projection epilogue: n0<384 -> bf16 transposed into VT[b][384][Lvt]
//           (batch from row/Lvt), else bf16 into QK[row][n0-384+...], ld 1536.
// Requires M%64==0, N%64==0, K%64==0.
template<int MODE>
__global__ __launch_bounds__(256)
void gemm64(const u16* __restrict__ A, long sA, int lda,
            const u16* __restrict__ B, long sB, int ldb,
            void* __restrict__ Cv, long sC, int ldc,
            u16* __restrict__ VT, u16* __restrict__ QK, int Lvt,
            int K)
{
    __shared__ __align__(16) u16 As[2][4096];
    __shared__ __align__(16) u16 Bs[2][4096];

    const int z  = blockIdx.z;
    const int m0 = blockIdx.x * 64;
    const int n0 = blockIdx.y * 64;
    A += (long)z * sA + (long)m0 * lda;
    B += (long)z * sB + (long)n0 * ldb;

    const int tid  = threadIdx.x;
    const int wid  = tid >> 6;
    const int lane = tid & 63;
    const int wr = wid >> 1, wc = wid & 1;
    const int lane15 = lane & 15;
    const int lq = lane >> 4;                // 0..3

    // staging granule ids for this thread: g0 = wid*64+lane, g1 = g0+256
    const int g0 = wid * 64 + lane;

    f32x4 acc[2][2];
    #pragma unroll
    for (int i = 0; i < 2; ++i)
        #pragma unroll
        for (int j = 0; j < 2; ++j)
            acc[i][j] = (f32x4){0.f, 0.f, 0.f, 0.f};

    // stage one 64x64 tile (8 KB): 2 granules (16B) per thread per matrix
    auto stage = [&](const u16* __restrict__ G, int ld, int k0, u16* lds) {
        #pragma unroll
        for (int h = 0; h < 2; ++h) {
            const int gid  = g0 + h * 256;
            const int row  = gid >> 3;
            const int slot = (gid & 7) ^ (row & 7);     // pre-swizzled source
            const u16* src = G + (long)row * ld + k0 + slot * 8;
            u16* dst = lds + wid * 512 + h * 2048;      // wave-uniform base
            __builtin_amdgcn_global_load_lds(
                (const __attribute__((address_space(1))) void*)src,
                (__attribute__((address_space(3))) void*)dst, 16, 0, 0);
        }
    };
    // swizzled read of granule (row, colslot)
    auto rd = [&](const u16* lds, int row, int colslot) -> short8 {
        const int byt = row * 128 + (((colslot) ^ (row & 7)) << 4);
        return *reinterpret_cast<const short8*>(
            reinterpret_cast<const char*>(lds) + byt);
    };

    stage(A, lda, 0, As[0]);
    stage(B, ldb, 0, Bs[0]);
    __syncthreads();

    const int nt = K >> 6;
    int cur = 0;
    for (int t = 0; t < nt; ++t) {
        if (t + 1 < nt) {                   // prefetch next tile into buf^1
            stage(A, lda, (t + 1) << 6, As[cur ^ 1]);
            stage(B, ldb, (t + 1) << 6, Bs[cur ^ 1]);
        }
        short8 af[2][2], bf[2][2];
        #pragma unroll
        for (int mi = 0; mi < 2; ++mi)
            #pragma unroll
            for (int kk = 0; kk < 2; ++kk)
                af[mi][kk] = rd(As[cur], wr * 32 + mi * 16 + lane15, kk * 4 + lq);
        #pragma unroll
        for (int ni = 0; ni < 2; ++ni)
            #pragma unroll
            for (int kk = 0; kk < 2; ++kk)
                bf[ni][kk] = rd(Bs[cur], wc * 32 + ni * 16 + lane15, kk * 4 + lq);
        #pragma unroll
        for (int mi = 0; mi < 2; ++mi)
            #pragma unroll
            for (int ni = 0; ni < 2; ++ni)
                #pragma unroll
                for (int kk = 0; kk < 2; ++kk)
                    acc[mi][ni] = __builtin_amdgcn_mfma_f32_16x16x32_bf16(
                        af[mi][kk], bf[ni][kk], acc[mi][ni], 0, 0, 0);
        __syncthreads();   // drains vmcnt (next tile staged) + lgkm (reads done)
        cur ^= 1;
    }

    // epilogue. C/D frag: col = lane&15, row = (lane>>4)*4 + reg  [m89]
    const int r0 = lq * 4;
    if (MODE == 0 || MODE == 1) {
        float* C = (float*)Cv + (long)z * sC;
        #pragma unroll
        for (int mi = 0; mi < 2; ++mi)
            #pragma unroll
            for (int r = 0; r < 4; ++r) {
                const int row = m0 + wr * 32 + mi * 16 + r0 + r;
                float* crow = C + (long)row * ldc + n0 + wc * 32 + lane15;
                #pragma unroll
                for (int ni = 0; ni < 2; ++ni) {
                    if (MODE == 1) crow[ni * 16] += acc[mi][ni][r];
                    else           crow[ni * 16]  = acc[mi][ni][r];
                }
            }
    } else {
        if (n0 < 384) {
            // V columns -> transposed bf16: VT[(bz*384 + col)*Lvt + l]
            #pragma unroll
            for (int mi = 0; mi < 2; ++mi) {
                const int row = m0 + wr * 32 + mi * 16 + r0;
                const int bz = row / Lvt;
                const int l  = row % Lvt;
                #pragma unroll
                for (int ni = 0; ni < 2; ++ni) {
                    const int col = n0 + wc * 32 + ni * 16 + lane15;
                    u32 lo = (u32)f2bf(acc[mi][ni][0]) | ((u32)f2bf(acc[mi][ni][1]) << 16);
                    u32 hi = (u32)f2bf(acc[mi][ni][2]) | ((u32)f2bf(acc[mi][ni][3]) << 16);
                    uint2 pk; pk.x = lo; pk.y = hi;
                    *reinterpret_cast<uint2*>(VT + ((long)bz * 384 + col) * Lvt + l) = pk;
                }
            }
        } else {
            // Q/K columns -> packed bf16 [row][1536]
            #pragma unroll
            for (int mi = 0; mi < 2; ++mi)
                #pragma unroll
                for (int r = 0; r < 4; ++r) {
                    const int row = m0 + wr * 32 + mi * 16 + r0 + r;
                    u16* qrow = QK + (long)row * 1536 + (n0 - 384) + wc * 32 + lane15;
                    #pragma unroll
                    for (int ni = 0; ni < 2; ++ni)
                        qrow[ni * 16] = f2bf(acc[mi][ni][r]);
                }
        }
    }
}

// ============ small fp32-accum GEMM for qe/qp bias tables ============
// C[M,N] = A[M,K](bf16, lda) . B[N,K](f32)^T
__global__ __launch_bounds__(256)
void gemm_bias(const u16* __restrict__ A, int lda, const float* __restrict__ B,
               float* __restrict__ C, int M, int N, int K)
{
    __shared__ float As[16][64];
    __shared__ float Bs[16][64];
    const int m0 = blockIdx.x * 64;
    const int n0 = blockIdx.y * 64;
    const int tid = threadIdx.x;
    const int tx = tid & 15, ty = tid >> 4;
    const int ar = tid >> 2;
    const int ak = (tid & 3) << 2;

    float acc[4][4] = {{0.f,0.f,0.f,0.f},{0.f,0.f,0.f,0.f},
                       {0.f,0.f,0.f,0.f},{0.f,0.f,0.f,0.f}};

    for (int k0 = 0; k0 < K; k0 += 16) {
        const u16* ap = A + (long)(m0 + ar) * lda + (k0 + ak);
        ushort4 a4 = *reinterpret_cast<const ushort4*>(ap);
        As[ak+0][ar] = bf2f(a4.x); As[ak+1][ar] = bf2f(a4.y);
        As[ak+2][ar] = bf2f(a4.z); As[ak+3][ar] = bf2f(a4.w);

        float4 bv = make_float4(0.f,0.f,0.f,0.f);
        if (n0 + ar < N) bv = ld4f(B + (long)(n0 + ar) * K + (k0 + ak));
        Bs[ak+0][ar] = bv.x; Bs[ak+1][ar] = bv.y;
        Bs[ak+2][ar] = bv.z; Bs[ak+3][ar] = bv.w;
        __syncthreads();

        #pragma unroll
        for (int kk = 0; kk < 16; ++kk) {
            float4 af = ld4f(&As[kk][ty * 4]);
            float4 bfv = ld4f(&Bs[kk][tx * 4]);
            float a[4] = {af.x, af.y, af.z, af.w};
            float b[4] = {bfv.x, bfv.y, bfv.z, bfv.w};
            #pragma unroll
            for (int i = 0; i < 4; ++i)
                #pragma unroll
                for (int j = 0; j < 4; ++j)
                    acc[i][j] = fmaf(a[i], b[j], acc[i][j]);
        }
        __syncthreads();
    }
    #pragma unroll
    for (int i = 0; i < 4; ++i) {
        const int row = m0 + ty * 4 + i;
        float* crow = C + (long)row * N;
        #pragma unroll
        for (int j = 0; j < 4; ++j) {
            const int col = n0 + tx * 4 + j;
            if (col < N) crow[col] = acc[i][j];
        }
    }
}

// ============ softmax kernels (fp32 in, bf16 probs out) ============

__device__ __forceinline__ float blockReduceMax(float v, float* red, int tid) {
    #pragma unroll
    for (int o = 32; o >= 1; o >>= 1) v = fmaxf(v, __shfl_xor(v, o));
    if ((tid & 63) == 0) red[tid >> 6] = v;
    __syncthreads();
    return fmaxf(fmaxf(red[0], red[1]), fmaxf(red[2], red[3]));
}
__device__ __forceinline__ float blockReduceSum(float v, float* red, int tid) {
    #pragma unroll
    for (int o = 32; o >= 1; o >>= 1) v += __shfl_xor(v, o);
    if ((tid & 63) == 0) red[4 + (tid >> 6)] = v;
    __syncthreads();
    return red[4] + red[5] + red[6] + red[7];
}

__global__ __launch_bounds__(256)
void softmax_h2h(const float* __restrict__ S, u16* __restrict__ P,
                 const float* __restrict__ qe, const int* __restrict__ mask,
                 float scale)
{
    const int i = blockIdx.x, b = blockIdx.y;
    const long roff = (long)b * 512 + i;
    const float* row = S + roff * 512;
    u16* prow = P + roff * 512;
    const int* mrow = mask + roff * 512;
    __shared__ float qsh[64];
    __shared__ float red[8];
    const int tid = threadIdx.x;
    if (tid < 64) qsh[tid] = qe[roff * 64 + tid];
    __syncthreads();

    float x[2]; float mx = -1e30f;
    #pragma unroll
    for (int t = 0; t < 2; ++t) {
        const int j = tid + t * 256;
        const int m = mrow[j];
        float v = (row[j] + qsh[m]) * scale - 10000.f * (m == 0 ? 1.f : 0.f);
        x[t] = v; mx = fmaxf(mx, v);
    }
    mx = blockReduceMax(mx, red, tid);
    float s = 0.f;
    #pragma unroll
    for (int t = 0; t < 2; ++t) { x[t] = __expf(x[t] - mx); s += x[t]; }
    s = blockReduceSum(s, red, tid);
    const float inv = 1.f / s;
    #pragma unroll
    for (int t = 0; t < 2; ++t) prow[tid + t * 256] = f2bf(x[t] * inv);
}

__global__ __launch_bounds__(256)
void softmax_t2t(const float* __restrict__ S, u16* __restrict__ P,
                 const float* __restrict__ qp, const float* __restrict__ mask,
                 float scale)
{
    const int i = blockIdx.x, b = blockIdx.y;
    const long roff = (long)b * 1024 + i;
    const float* row = S + roff * 1024;
    u16* prow = P + roff * 1024;
    const float* mrow = mask + roff * 1024;
    __shared__ float qsh[13];
    __shared__ float red[8];
    const int tid = threadIdx.x;
    if (tid < 13) qsh[tid] = qp[roff * 13 + tid];
    __syncthreads();

    float x[4]; float mx = -1e30f;
    #pragma unroll
    for (int t = 0; t < 4; ++t) {
        const int j = tid + t * 256;
        int pos = j - i;
        pos = (pos < -6 ? -6 : (pos > 6 ? 6 : pos)) + 6;
        float v = (row[j] + qsh[pos]) * scale - 10000.f * mrow[j];
        x[t] = v; mx = fmaxf(mx, v);
    }
    mx = blockReduceMax(mx, red, tid);
    float s = 0.f;
    #pragma unroll
    for (int t = 0; t < 4; ++t) { x[t] = __expf(x[t] - mx); s += x[t]; }
    s = blockReduceSum(s, red, tid);
    const float inv = 1.f / s;
    #pragma unroll
    for (int t = 0; t < 4; ++t) prow[tid + t * 256] = f2bf(x[t] * inv);
}

template<int L, bool HASMASK>
__global__ __launch_bounds__(256)
void softmax_plain(const float* __restrict__ S, u16* __restrict__ P,
                   const float* __restrict__ mask, float scale)
{
    const int i = blockIdx.x, b = blockIdx.y;
    const long roff = ((long)b * gridDim.x + i) * L;
    const float* row = S + roff;
    u16* prow = P + roff;
    const float* mrow = HASMASK ? (mask + roff) : nullptr;
    __shared__ float red[8];
    const int tid = threadIdx.x;
    constexpr int NV = L / 256;

    float x[NV]; float mx = -1e30f;
    #pragma unroll
    for (int t = 0; t < NV; ++t) {
        const int j = tid + t * 256;
        float v = row[j] * scale;
        if (HASMASK) v -= 10000.f * mrow[j];
        x[t] = v; mx = fmaxf(mx, v);
    }
    mx = blockReduceMax(mx, red, tid);
    float s = 0.f;
    #pragma unroll
    for (int t = 0; t < NV; ++t) { x[t] = __expf(x[t] - mx); s += x[t]; }
    s = blockReduceSum(s, red, tid);
    const float inv = 1.f / s;
    #pragma unroll
    for (int t = 0; t < NV; ++t) prow[tid + t * 256] = f2bf(x[t] * inv);
}

// ============ host side ============

extern "C" void kernel_launch(void* const* d_in, const int* in_sizes, int n_in,
                              void* d_out, int out_size, void* d_ws, size_t ws_size,
                              hipStream_t stream)
{
    const int Bn = 4, Lt = 1024, Lh = 512, Dd = 384;
    const float scale = 0.05103103630798288f;  // 1/sqrt(384)

    const float* text    = (const float*)d_in[0];
    const float* html    = (const float*)d_in[1];
    const int*   H2Hmask = (const int*)  d_in[2];
    const float* T2Tmask = (const float*)d_in[3];
    const float* H2Tmask = (const float*)d_in[4];
    const float* posemb  = (const float*)d_in[6];
    const float* edgeemb = (const float*)d_in[7];
    float* out = (float*)d_out;

    // ---- workspace carve (256B-aligned) ----
    char* p = (char*)d_ws;
    auto au16 = [&](long n) { u16* r = (u16*)p;  p += ((n * 2 + 255) & ~255L); return r; };
    auto af32 = [&](long n) { float* r = (float*)p; p += ((n * 4 + 255) & ~255L); return r; };

    const long nT = (long)Bn * Lt * Dd;   // 1572864
    const long nH = (long)Bn * Lh * Dd;   //  786432
    u16* text_bf = au16(nT);
    u16* html_bf = au16(nH);
    u16* WTtext  = au16(5L * 384 * 384);  // [1920][384]: V_T,K_H2T,Q_T2H,Q_T2T,K_T2T
    u16* WThtml  = au16(5L * 384 * 384);  // [1920][384]: V_H,Q_H2H,K_H2H,Q_H2T,K_T2H
    u16* textQK  = au16((long)Bn * Lt * 1536);
    u16* htmlQK  = au16((long)Bn * Lh * 1536);
    u16* text_vT = au16(nT);              // [B][384][Lt]
    u16* html_vT = au16(nH);              // [B][384][Lh]
    float* qe = af32((long)Bn * Lh * 64);
    float* qp = af32((long)Bn * Lt * 13);
    float* scores = af32((long)Bn * Lt * Lt);
    u16*   probs  = au16((long)Bn * Lt * Lt);

    // ---- conversions ----
    cvt2<<<2048, 256, 0, stream>>>((const float4*)text, (int)(nT / 4),
                                   (const float4*)html, (int)(nH / 4),
                                   text_bf, html_bf);
    WP wp; WD wd;
    for (int i = 0; i < 10; ++i) wp.p[i] = (const float*)d_in[8 + i];
    const long WSZ = 147456;  // 384*384
    wd.d[0] = WTtext + 0 * WSZ;  // W_V_T
    wd.d[1] = WThtml + 0 * WSZ;  // W_V_H
    wd.d[2] = WThtml + 1 * WSZ;  // W_Q_H2H
    wd.d[3] = WThtml + 2 * WSZ;  // W_K_H2H
    wd.d[4] = WThtml + 3 * WSZ;  // W_Q_H2T
    wd.d[5] = WTtext + 1 * WSZ;  // W_K_H2T
    wd.d[6] = WTtext + 2 * WSZ;  // W_Q_T2H
    wd.d[7] = WThtml + 4 * WSZ;  // W_K_T2H
    wd.d[8] = WTtext + 3 * WSZ;  // W_Q_T2T
    wd.d[9] = WTtext + 4 * WSZ;  // W_K_T2T
    wtrans<<<dim3(12, 12, 10), dim3(32, 32), 0, stream>>>(wp, wd);

    auto g64 = [&](int mode, const u16* A, long sA, int lda,
                   const u16* B, long sB, int ldb,
                   void* C, long sC, int ldc,
                   u16* VT, u16* QK, int Lvt,
                   int M, int N, int K, int batch) {
        dim3 g(M / 64, N / 64, batch), blk(256);
        switch (mode) {
        case 0: gemm64<0><<<g, blk, 0, stream>>>(A, sA, lda, B, sB, ldb, C, sC, ldc, VT, QK, Lvt, K); break;
        case 1: gemm64<1><<<g, blk, 0, stream>>>(A, sA, lda, B, sB, ldb, C, sC, ldc, VT, QK, Lvt, K); break;
        default: gemm64<4><<<g, blk, 0, stream>>>(A, sA, lda, B, sB, ldb, C, sC, ldc, VT, QK, Lvt, K); break;
        }
    };

    // ---- merged projections (V transposed out + packed QK out) ----
    // text: cols 0-383 V_T -> text_vT; 384.. -> textQK[row][0:1536]
    g64(4, text_bf, 0, 384, WTtext, 0, 384, nullptr, 0, 0,
        text_vT, textQK, Lt, Bn * Lt, 1920, 384, 1);
    g64(4, html_bf, 0, 384, WThtml, 0, 384, nullptr, 0, 0,
        html_vT, htmlQK, Lh, Bn * Lh, 1920, 384, 1);

    // packed QK column offsets (block i of W-concat -> col (i-1)*384)
    u16* h2h_q = htmlQK + 0;     u16* h2h_k = htmlQK + 384;
    u16* h2t_q = htmlQK + 768;   u16* t2h_k = htmlQK + 1152;
    u16* h2t_k = textQK + 0;     u16* t2h_q = textQK + 384;
    u16* t2t_q = textQK + 768;   u16* t2t_k = textQK + 1152;

    // ---- bias tables ----
    gemm_bias<<<dim3((Bn * Lh) / 64, 1), 256, 0, stream>>>(h2h_q, 1536, edgeemb, qe, Bn * Lh, 64, Dd);
    gemm_bias<<<dim3((Bn * Lt) / 64, 1), 256, 0, stream>>>(t2t_q, 1536, posemb,  qp, Bn * Lt, 13, Dd);

    const long sQt = (long)Lt * 1536, sQh = (long)Lh * 1536;
    const long sVt = (long)Dd * Lt,  sVh = (long)Dd * Lh;
    const long sOut = (long)(Lt + Lh) * Dd;
    float* outH = out + (long)Lt * Dd;

    // ---- H2H ----
    g64(0, h2h_q, sQh, 1536, h2h_k, sQh, 1536, scores, (long)Lh * Lh, Lh,
        nullptr, nullptr, 0, Lh, Lh, Dd, Bn);
    softmax_h2h<<<dim3(Lh, Bn), 256, 0, stream>>>(scores, probs, qe, H2Hmask, scale);
    g64(0, probs, (long)Lh * Lh, Lh, html_vT, sVh, Lh, outH, sOut, Dd,
        nullptr, nullptr, 0, Lh, Dd, Lh, Bn);

    // ---- H2T ----
    g64(0, h2t_q, sQh, 1536, h2t_k, sQt, 1536, scores, (long)Lh * Lt, Lt,
        nullptr, nullptr, 0, Lh, Lt, Dd, Bn);
    softmax_plain<1024, true><<<dim3(Lh, Bn), 256, 0, stream>>>(scores, probs, H2Tmask, scale);
    g64(1, probs, (long)Lh * Lt, Lt, text_vT, sVt, Lt, outH, sOut, Dd,
        nullptr, nullptr, 0, Lh, Dd, Lt, Bn);

    // ---- T2H ----
    g64(0, t2h_q, sQt, 1536, t2h_k, sQh, 1536, scores, (long)Lt * Lh, Lh,
        nullptr, nullptr, 0, Lt, Lh, Dd, Bn);
    softmax_plain<512, false><<<dim3(Lt, Bn), 256, 0, stream>>>(scores, probs, nullptr, scale);
    g64(0, probs, (long)Lt * Lh, Lh, html_vT, sVh, Lh, out, sOut, Dd,
        nullptr, nullptr, 0, Lt, Dd, Lh, Bn);

    // ---- T2T ----
    g64(0, t2t_q, sQt, 1536, t2t_k, sQt, 1536, scores, (long)Lt * Lt, Lt,
        nullptr, nullptr, 0, Lt, Lt, Dd, Bn);
    softmax_t2t<<<dim3(Lt, Bn), 256, 0, stream>>>(scores, probs, qp, T2Tmask, scale);
    g64(1, probs, (long)Lt * Lt, Lt, text_vT, sVt, Lt, out, sOut, Dd,
        nullptr, nullptr, 0, Lt, Dd, Lt, Bn);
}

// Round 6
// 215.942 us; speedup vs baseline: 3.6222x; 1.3066x over previous
//
#include <hip/hip_runtime.h>
#include <math.h>

typedef unsigned short u16;
typedef unsigned int u32;
typedef __attribute__((ext_vector_type(8))) short short8;
typedef __attribute__((ext_vector_type(4))) float f32x4;

__device__ __forceinline__ u16 f2bf(float f) {
    u32 u = __float_as_uint(f);
    u = (u + 0x7FFFu + ((u >> 16) & 1u)) >> 16;   // RNE
    return (u16)u;
}
__device__ __forceinline__ float bf2f(u16 h) {
    return __uint_as_float(((u32)h) << 16);
}
__device__ __forceinline__ float4 ld4f(const float* p) {
    return *reinterpret_cast<const float4*>(p);
}

// ============ conversion kernels ============

__global__ __launch_bounds__(256)
void cvt2(const float4* __restrict__ a, int na4,
          const float4* __restrict__ b, int nb4,
          u16* __restrict__ oa, u16* __restrict__ ob)
{
    int idx = blockIdx.x * 256 + threadIdx.x;
    const int tot = na4 + nb4;
    for (; idx < tot; idx += gridDim.x * 256) {
        float4 v; u16* o;
        if (idx < na4) { v = a[idx];        o = oa + (long)idx * 4; }
        else           { v = b[idx - na4];  o = ob + (long)(idx - na4) * 4; }
        u32 lo = (u32)f2bf(v.x) | ((u32)f2bf(v.y) << 16);
        u32 hi = (u32)f2bf(v.z) | ((u32)f2bf(v.w) << 16);
        uint2 pk; pk.x = lo; pk.y = hi;
        *reinterpret_cast<uint2*>(o) = pk;
    }
}

struct WP { const float* p[10]; };
struct WD { u16* d[10]; };

// W [384][384] fp32 -> W^T bf16 at per-weight destination
__global__ __launch_bounds__(1024)
void wtrans(WP w, WD wd)
{
    __shared__ float t[32][33];
    const int z = blockIdx.z;
    const float* W = w.p[z];
    const int k = blockIdx.x * 32 + threadIdx.y;   // row of W
    const int n = blockIdx.y * 32 + threadIdx.x;   // col of W
    t[threadIdx.y][threadIdx.x] = W[k * 384 + n];
    __syncthreads();
    const int no = blockIdx.y * 32 + threadIdx.y;
    const int ko = blockIdx.x * 32 + threadIdx.x;
    wd.d[z][no * 384 + ko] = f2bf(t[threadIdx.x][threadIdx.y]);
}

// ============ shared 64x64 MFMA NT core (verified r4->r5: identical absmax) ====
// Computes 64x64 C-tile of A[64 rows, lda] . B[64 rows, ldb]^T over K (K%64==0).
// Double-buffered LDS, XOR-swizzled granules, global_load_lds width 16.
__device__ __forceinline__ void mfma_core64(
    const u16* __restrict__ A, int lda,
    const u16* __restrict__ B, int ldb, int K,
    u16 (&As)[2][4096], u16 (&Bs)[2][4096],
    f32x4 (&acc)[2][2])
{
    const int tid  = threadIdx.x;
    const int wid  = tid >> 6;
    const int lane = tid & 63;
    const int wr = wid >> 1, wc = wid & 1;
    const int lane15 = lane & 15;
    const int lq = lane >> 4;
    const int g0 = wid * 64 + lane;

    #pragma unroll
    for (int i = 0; i < 2; ++i)
        #pragma unroll
        for (int j = 0; j < 2; ++j)
            acc[i][j] = (f32x4){0.f, 0.f, 0.f, 0.f};

    auto stage = [&](const u16* __restrict__ G, int ld, int k0, u16* lds) {
        #pragma unroll
        for (int h = 0; h < 2; ++h) {
            const int gid  = g0 + h * 256;
            const int row  = gid >> 3;
            const int slot = (gid & 7) ^ (row & 7);     // pre-swizzled source
            const u16* src = G + (long)row * ld + k0 + slot * 8;
            u16* dst = lds + wid * 512 + h * 2048;      // wave-uniform base
            __builtin_amdgcn_global_load_lds(
                (const __attribute__((address_space(1))) void*)src,
                (__attribute__((address_space(3))) void*)dst, 16, 0, 0);
        }
    };
    auto rd = [&](const u16* lds, int row, int colslot) -> short8 {
        const int byt = row * 128 + ((colslot ^ (row & 7)) << 4);
        return *reinterpret_cast<const short8*>(
            reinterpret_cast<const char*>(lds) + byt);
    };

    stage(A, lda, 0, As[0]);
    stage(B, ldb, 0, Bs[0]);
    __syncthreads();

    const int nt = K >> 6;
    int cur = 0;
    for (int t = 0; t < nt; ++t) {
        if (t + 1 < nt) {                   // prefetch next tile into buf^1
            stage(A, lda, (t + 1) << 6, As[cur ^ 1]);
            stage(B, ldb, (t + 1) << 6, Bs[cur ^ 1]);
        }
        short8 af[2][2], bf[2][2];
        #pragma unroll
        for (int mi = 0; mi < 2; ++mi)
            #pragma unroll
            for (int kk = 0; kk < 2; ++kk)
                af[mi][kk] = rd(As[cur], wr * 32 + mi * 16 + lane15, kk * 4 + lq);
        #pragma unroll
        for (int ni = 0; ni < 2; ++ni)
            #pragma unroll
            for (int kk = 0; kk < 2; ++kk)
                bf[ni][kk] = rd(Bs[cur], wc * 32 + ni * 16 + lane15, kk * 4 + lq);
        #pragma unroll
        for (int mi = 0; mi < 2; ++mi)
            #pragma unroll
            for (int ni = 0; ni < 2; ++ni)
                #pragma unroll
                for (int kk = 0; kk < 2; ++kk)
                    acc[mi][ni] = __builtin_amdgcn_mfma_f32_16x16x32_bf16(
                        af[mi][kk], bf[ni][kk], acc[mi][ni], 0, 0, 0);
        __syncthreads();
        cur ^= 1;
    }
}

// ============ grouped f32-output GEMM (scores / PV) ============
struct Seg {
    const u16* A; const u16* B; float* C;
    long sA, sB, sC;
    int lda, ldb, ldc, K, nbx, nbxSh, start, pad;
};
struct Segs { Seg s[4]; };

template<int NSEG>
__global__ __launch_bounds__(256)
void gemm_grouped(Segs d)
{
    __shared__ __align__(16) u16 As[2][4096];
    __shared__ __align__(16) u16 Bs[2][4096];
    const int bid = blockIdx.x;
    Seg sg = d.s[0];                         // static-index selects only
    if (NSEG > 1 && bid >= d.s[1].start) sg = d.s[1];
    if (NSEG > 2 && bid >= d.s[2].start) sg = d.s[2];
    if (NSEG > 3 && bid >= d.s[3].start) sg = d.s[3];

    const int local = bid - sg.start;
    const int bx = local & (sg.nbx - 1);
    const int by = local >> sg.nbxSh;
    const int z  = blockIdx.y;
    const int m0 = bx * 64, n0 = by * 64;

    const u16* A = sg.A + (long)z * sg.sA + (long)m0 * sg.lda;
    const u16* B = sg.B + (long)z * sg.sB + (long)n0 * sg.ldb;

    f32x4 acc[2][2];
    mfma_core64(A, sg.lda, B, sg.ldb, sg.K, As, Bs, acc);

    const int tid = threadIdx.x;
    const int wid = tid >> 6, lane = tid & 63;
    const int wr = wid >> 1, wc = wid & 1;
    const int lane15 = lane & 15;
    const int r0 = (lane >> 4) * 4;

    float* C = sg.C + (long)z * sg.sC;
    #pragma unroll
    for (int mi = 0; mi < 2; ++mi)
        #pragma unroll
        for (int r = 0; r < 4; ++r) {
            const int row = m0 + wr * 32 + mi * 16 + r0 + r;
            float* crow = C + (long)row * sg.ldc + n0 + wc * 32 + lane15;
            #pragma unroll
            for (int ni = 0; ni < 2; ++ni)
                crow[ni * 16] = acc[mi][ni][r];
        }
}

// ============ grouped projection GEMM (V^T + packed QK epilogue) ============
struct PSeg {
    const u16* A; const u16* Bw; u16* QK; u16* VT;
    int lvtSh, vtOff, nbx, nbxSh, start, pad;
};
struct PSegs { PSeg s[2]; };

__global__ __launch_bounds__(256)
void proj_grouped(PSegs d)
{
    __shared__ __align__(16) u16 As[2][4096];
    __shared__ __align__(16) u16 Bs[2][4096];
    const int bid = blockIdx.x;
    PSeg sg = d.s[0];
    if (bid >= d.s[1].start) sg = d.s[1];

    const int local = bid - sg.start;
    const int bx = local & (sg.nbx - 1);
    const int by = local >> sg.nbxSh;
    const int m0 = bx * 64, n0 = by * 64;

    const u16* A = sg.A + (long)m0 * 384;
    const u16* B = sg.Bw + (long)n0 * 384;

    f32x4 acc[2][2];
    mfma_core64(A, 384, B, 384, 384, As, Bs, acc);

    const int tid = threadIdx.x;
    const int wid = tid >> 6, lane = tid & 63;
    const int wr = wid >> 1, wc = wid & 1;
    const int lane15 = lane & 15;
    const int r0 = (lane >> 4) * 4;
    const int lmask = (1 << sg.lvtSh) - 1;

    if (n0 < 384) {
        // V columns -> stacked transposed bf16: VT[(bz*384+col)*1536 + vtOff + l]
        #pragma unroll
        for (int mi = 0; mi < 2; ++mi) {
            const int row = m0 + wr * 32 + mi * 16 + r0;
            const int bz = row >> sg.lvtSh;
            const int l  = row & lmask;
            #pragma unroll
            for (int ni = 0; ni < 2; ++ni) {
                const int col = n0 + wc * 32 + ni * 16 + lane15;
                u32 lo = (u32)f2bf(acc[mi][ni][0]) | ((u32)f2bf(acc[mi][ni][1]) << 16);
                u32 hi = (u32)f2bf(acc[mi][ni][2]) | ((u32)f2bf(acc[mi][ni][3]) << 16);
                uint2 pk; pk.x = lo; pk.y = hi;
                *reinterpret_cast<uint2*>(
                    sg.VT + ((long)bz * 384 + col) * 1536 + sg.vtOff + l) = pk;
            }
        }
    } else {
        // Q/K columns -> packed bf16 [row][1536]
        #pragma unroll
        for (int mi = 0; mi < 2; ++mi)
            #pragma unroll
            for (int r = 0; r < 4; ++r) {
                const int row = m0 + wr * 32 + mi * 16 + r0 + r;
                u16* qrow = sg.QK + (long)row * 1536 + (n0 - 384) + wc * 32 + lane15;
                #pragma unroll
                for (int ni = 0; ni < 2; ++ni)
                    qrow[ni * 16] = f2bf(acc[mi][ni][r]);
            }
    }
}

// ============ merged bias-table GEMM (qe & qp in one launch) ============
// C[M,N] = A[M,384](bf16, ld 1536) . B[N,384](f32)^T ; seg0 blocks 0-31, seg1 32-95.
__global__ __launch_bounds__(256)
void gemm_bias2(const u16* __restrict__ A0, const float* __restrict__ B0,
                float* __restrict__ C0, int N0,
                const u16* __restrict__ A1, const float* __restrict__ B1,
                float* __restrict__ C1, int N1)
{
    __shared__ float As[16][64];
    __shared__ float Bs[16][64];
    const int bid = blockIdx.x;
    const u16* A; const float* B; float* C; int N, m0;
    if (bid < 32) { A = A0; B = B0; C = C0; N = N0; m0 = bid * 64; }
    else          { A = A1; B = B1; C = C1; N = N1; m0 = (bid - 32) * 64; }

    const int tid = threadIdx.x;
    const int tx = tid & 15, ty = tid >> 4;
    const int ar = tid >> 2;
    const int ak = (tid & 3) << 2;

    float acc[4][4] = {{0.f,0.f,0.f,0.f},{0.f,0.f,0.f,0.f},
                       {0.f,0.f,0.f,0.f},{0.f,0.f,0.f,0.f}};

    for (int k0 = 0; k0 < 384; k0 += 16) {
        const u16* ap = A + (long)(m0 + ar) * 1536 + (k0 + ak);
        ushort4 a4 = *reinterpret_cast<const ushort4*>(ap);
        As[ak+0][ar] = bf2f(a4.x); As[ak+1][ar] = bf2f(a4.y);
        As[ak+2][ar] = bf2f(a4.z); As[ak+3][ar] = bf2f(a4.w);

        float4 bv = make_float4(0.f,0.f,0.f,0.f);
        if (ar < N) bv = ld4f(B + (long)ar * 384 + (k0 + ak));
        Bs[ak+0][ar] = bv.x; Bs[ak+1][ar] = bv.y;
        Bs[ak+2][ar] = bv.z; Bs[ak+3][ar] = bv.w;
        __syncthreads();

        #pragma unroll
        for (int kk = 0; kk < 16; ++kk) {
            float4 af = ld4f(&As[kk][ty * 4]);
            float4 bfv = ld4f(&Bs[kk][tx * 4]);
            float a[4] = {af.x, af.y, af.z, af.w};
            float b[4] = {bfv.x, bfv.y, bfv.z, bfv.w};
            #pragma unroll
            for (int i = 0; i < 4; ++i)
                #pragma unroll
                for (int j = 0; j < 4; ++j)
                    acc[i][j] = fmaf(a[i], b[j], acc[i][j]);
        }
        __syncthreads();
    }
    #pragma unroll
    for (int i = 0; i < 4; ++i) {
        const int row = m0 + ty * 4 + i;
        float* crow = C + (long)row * N;
        #pragma unroll
        for (int j = 0; j < 4; ++j) {
            const int col = tx * 4 + j;
            if (col < N) crow[col] = acc[i][j];
        }
    }
}

// ============ fused softmax: one block per output row, two segments ============

__device__ __forceinline__ float blockReduceMax(float v, float* red, int tid) {
    #pragma unroll
    for (int o = 32; o >= 1; o >>= 1) v = fmaxf(v, __shfl_xor(v, o));
    if ((tid & 63) == 0) red[tid >> 6] = v;
    __syncthreads();
    return fmaxf(fmaxf(red[0], red[1]), fmaxf(red[2], red[3]));
}
__device__ __forceinline__ float blockReduceSum(float v, float* red, int tid) {
    #pragma unroll
    for (int o = 32; o >= 1; o >>= 1) v += __shfl_xor(v, o);
    if ((tid & 63) == 0) red[4 + (tid >> 6)] = v;
    __syncthreads();
    return red[4] + red[5] + red[6] + red[7];
}

// blocks 0..2047: html rows (h2h cols 0-511, h2t cols 512-1535)
// blocks 2048..6143: text rows (t2h cols 0-511, t2t cols 512-1535)
__global__ __launch_bounds__(256)
void softmax_fused(const float* __restrict__ scoresH, u16* __restrict__ probsH,
                   const float* __restrict__ scoresT, u16* __restrict__ probsT,
                   const float* __restrict__ qe, const float* __restrict__ qp,
                   const int* __restrict__ H2Hmask,
                   const float* __restrict__ H2Tmask,
                   const float* __restrict__ T2Tmask, float scale)
{
    const int bid = blockIdx.x;
    const int tid = threadIdx.x;
    __shared__ float qsh[64];
    __shared__ float red[8];

    if (bid < 2048) {
        const int b = bid >> 9, i = bid & 511;
        const long rbase = ((long)b * 512 + i) * 1536;
        const float* rowS = scoresH + rbase;
        u16* rowP = probsH + rbase;
        const int*   mrow  = H2Hmask + ((long)b * 512 + i) * 512;
        const float* m2row = H2Tmask + ((long)b * 512 + i) * 1024;
        if (tid < 64) qsh[tid] = qe[((long)b * 512 + i) * 64 + tid];
        __syncthreads();

        // --- h2h (512) ---
        float x[2]; float mx = -1e30f;
        #pragma unroll
        for (int t = 0; t < 2; ++t) {
            const int j = tid + t * 256;
            const int m = mrow[j];
            float v = (rowS[j] + qsh[m]) * scale - 10000.f * (m == 0 ? 1.f : 0.f);
            x[t] = v; mx = fmaxf(mx, v);
        }
        mx = blockReduceMax(mx, red, tid);
        float s = 0.f;
        #pragma unroll
        for (int t = 0; t < 2; ++t) { x[t] = __expf(x[t] - mx); s += x[t]; }
        s = blockReduceSum(s, red, tid);
        float inv = 1.f / s;
        #pragma unroll
        for (int t = 0; t < 2; ++t) rowP[tid + t * 256] = f2bf(x[t] * inv);

        // --- h2t (1024, cols 512..1535) ---
        float y[4]; mx = -1e30f;
        #pragma unroll
        for (int t = 0; t < 4; ++t) {
            const int jj = tid + t * 256;
            float v = rowS[512 + jj] * scale - 10000.f * m2row[jj];
            y[t] = v; mx = fmaxf(mx, v);
        }
        mx = blockReduceMax(mx, red, tid);
        s = 0.f;
        #pragma unroll
        for (int t = 0; t < 4; ++t) { y[t] = __expf(y[t] - mx); s += y[t]; }
        s = blockReduceSum(s, red, tid);
        inv = 1.f / s;
        #pragma unroll
        for (int t = 0; t < 4; ++t) rowP[512 + tid + t * 256] = f2bf(y[t] * inv);
    } else {
        const int bid2 = bid - 2048;
        const int b = bid2 >> 10, i = bid2 & 1023;
        const long rbase = ((long)b * 1024 + i) * 1536;
        const float* rowS = scoresT + rbase;
        u16* rowP = probsT + rbase;
        const float* m2row = T2Tmask + ((long)b * 1024 + i) * 1024;
        if (tid < 13) qsh[tid] = qp[((long)b * 1024 + i) * 13 + tid];
        __syncthreads();

        // --- t2h (512, no mask) ---
        float x[2]; float mx = -1e30f;
        #pragma unroll
        for (int t = 0; t < 2; ++t) {
            const int j = tid + t * 256;
            float v = rowS[j] * scale;
            x[t] = v; mx = fmaxf(mx, v);
        }
        mx = blockReduceMax(mx, red, tid);
        float s = 0.f;
        #pragma unroll
        for (int t = 0; t < 2; ++t) { x[t] = __expf(x[t] - mx); s += x[t]; }
        s = blockReduceSum(s, red, tid);
        float inv = 1.f / s;
        #pragma unroll
        for (int t = 0; t < 2; ++t) rowP[tid + t * 256] = f2bf(x[t] * inv);

        // --- t2t (1024, cols 512..1535) ---
        float y[4]; mx = -1e30f;
        #pragma unroll
        for (int t = 0; t < 4; ++t) {
            const int jj = tid + t * 256;
            int pos = jj - i;
            pos = (pos < -6 ? -6 : (pos > 6 ? 6 : pos)) + 6;
            float v = (rowS[512 + jj] + qsh[pos]) * scale - 10000.f * m2row[jj];
            y[t] = v; mx = fmaxf(mx, v);
        }
        mx = blockReduceMax(mx, red, tid);
        s = 0.f;
        #pragma unroll
        for (int t = 0; t < 4; ++t) { y[t] = __expf(y[t] - mx); s += y[t]; }
        s = blockReduceSum(s, red, tid);
        inv = 1.f / s;
        #pragma unroll
        for (int t = 0; t < 4; ++t) rowP[512 + tid + t * 256] = f2bf(y[t] * inv);
    }
}

// ============ host side ============

extern "C" void kernel_launch(void* const* d_in, const int* in_sizes, int n_in,
                              void* d_out, int out_size, void* d_ws, size_t ws_size,
                              hipStream_t stream)
{
    const int Bn = 4, Lt = 1024, Lh = 512, Dd = 384;
    const float scale = 0.05103103630798288f;  // 1/sqrt(384)

    const float* text    = (const float*)d_in[0];
    const float* html    = (const float*)d_in[1];
    const int*   H2Hmask = (const int*)  d_in[2];
    const float* T2Tmask = (const float*)d_in[3];
    const float* H2Tmask = (const float*)d_in[4];
    const float* posemb  = (const float*)d_in[6];
    const float* edgeemb = (const float*)d_in[7];
    float* out = (float*)d_out;

    // ---- workspace carve (256B-aligned) ----
    char* p = (char*)d_ws;
    auto au16 = [&](long n) { u16* r = (u16*)p;  p += ((n * 2 + 255) & ~255L); return r; };
    auto af32 = [&](long n) { float* r = (float*)p; p += ((n * 4 + 255) & ~255L); return r; };

    const long nT = (long)Bn * Lt * Dd;   // 1572864
    const long nH = (long)Bn * Lh * Dd;   //  786432
    u16* text_bf = au16(nT);
    u16* html_bf = au16(nH);
    u16* WTtext  = au16(5L * 384 * 384);  // [1920][384]: V_T,K_H2T,Q_T2H,Q_T2T,K_T2T
    u16* WThtml  = au16(5L * 384 * 384);  // [1920][384]: V_H,Q_H2H,K_H2H,Q_H2T,K_T2H
    u16* textQK  = au16((long)Bn * Lt * 1536);
    u16* htmlQK  = au16((long)Bn * Lh * 1536);
    u16* VTs     = au16((long)Bn * 384 * 1536);  // [b][384][html_v^T | text_v^T]
    float* qe = af32((long)Bn * Lh * 64);
    float* qp = af32((long)Bn * Lt * 13);
    float* scoresH = af32((long)Bn * Lh * 1536); // [b][512][h2h(512)|h2t(1024)]
    float* scoresT = af32((long)Bn * Lt * 1536); // [b][1024][t2h(512)|t2t(1024)]
    u16* probsH = au16((long)Bn * Lh * 1536);
    u16* probsT = au16((long)Bn * Lt * 1536);

    // ---- 1-2: conversions ----
    cvt2<<<2048, 256, 0, stream>>>((const float4*)text, (int)(nT / 4),
                                   (const float4*)html, (int)(nH / 4),
                                   text_bf, html_bf);
    WP wp; WD wd;
    for (int i = 0; i < 10; ++i) wp.p[i] = (const float*)d_in[8 + i];
    const long WSZ = 147456;  // 384*384
    wd.d[0] = WTtext + 0 * WSZ;  // W_V_T
    wd.d[1] = WThtml + 0 * WSZ;  // W_V_H
    wd.d[2] = WThtml + 1 * WSZ;  // W_Q_H2H
    wd.d[3] = WThtml + 2 * WSZ;  // W_K_H2H
    wd.d[4] = WThtml + 3 * WSZ;  // W_Q_H2T
    wd.d[5] = WTtext + 1 * WSZ;  // W_K_H2T
    wd.d[6] = WTtext + 2 * WSZ;  // W_Q_T2H
    wd.d[7] = WThtml + 4 * WSZ;  // W_K_T2H
    wd.d[8] = WTtext + 3 * WSZ;  // W_Q_T2T
    wd.d[9] = WTtext + 4 * WSZ;  // W_K_T2T
    wtrans<<<dim3(12, 12, 10), dim3(32, 32), 0, stream>>>(wp, wd);

    // packed QK column offsets
    u16* h2h_q = htmlQK + 0;     u16* h2h_k = htmlQK + 384;
    u16* h2t_q = htmlQK + 768;   u16* t2h_k = htmlQK + 1152;
    u16* h2t_k = textQK + 0;     u16* t2h_q = textQK + 384;
    u16* t2t_q = textQK + 768;   u16* t2t_k = textQK + 1152;

    // ---- 3: grouped projections (text: 1920 blocks, html: 960) ----
    PSegs pj;
    pj.s[0] = { text_bf, WTtext, textQK, VTs, 10, 512, 64, 6, 0,    0 };
    pj.s[1] = { html_bf, WThtml, htmlQK, VTs,  9,   0, 32, 5, 1920, 0 };
    proj_grouped<<<2880, 256, 0, stream>>>(pj);

    // ---- 4: bias tables (qe 32 blocks + qp 64 blocks) ----
    gemm_bias2<<<96, 256, 0, stream>>>(h2h_q, edgeemb, qe, 64,
                                       t2t_q, posemb,  qp, 13);

    const long sQt = (long)Lt * 1536, sQh = (long)Lh * 1536;
    const long sSh = (long)Lh * 1536, sSt = (long)Lt * 1536;
    const long sV  = (long)384 * 1536;
    const long sOut = (long)(Lt + Lh) * 384;

    // ---- 5: grouped score GEMMs (576 xy-blocks x 4 batches) ----
    Segs sc;
    sc.s[0] = { h2h_q, h2h_k, scoresH,       sQh, sQh, sSh, 1536, 1536, 1536, 384,  8, 3,   0, 0 };
    sc.s[1] = { h2t_q, h2t_k, scoresH + 512, sQh, sQt, sSh, 1536, 1536, 1536, 384,  8, 3,  64, 0 };
    sc.s[2] = { t2h_q, t2h_k, scoresT,       sQt, sQh, sSt, 1536, 1536, 1536, 384, 16, 4, 192, 0 };
    sc.s[3] = { t2t_q, t2t_k, scoresT + 512, sQt, sQt, sSt, 1536, 1536, 1536, 384, 16, 4, 320, 0 };
    gemm_grouped<4><<<dim3(576, 4), 256, 0, stream>>>(sc);

    // ---- 6: fused softmax (2048 html rows + 4096 text rows) ----
    softmax_fused<<<6144, 256, 0, stream>>>(scoresH, probsH, scoresT, probsT,
                                            qe, qp, H2Hmask, H2Tmask, T2Tmask,
                                            scale);

    // ---- 7: grouped PV GEMMs (K=1536 stacked V) ----
    Segs pv;
    pv.s[0] = { probsH, VTs, out + (long)Lt * 384, sQh, sV, sOut, 1536, 1536, 384, 1536,  8, 3,  0, 0 };
    pv.s[1] = { probsT, VTs, out,                  sQt, sV, sOut, 1536, 1536, 384, 1536, 16, 4, 48, 0 };
    pv.s[2] = pv.s[1]; pv.s[3] = pv.s[1];  // unused (NSEG=2)
    gemm_grouped<2><<<dim3(144, 4), 256, 0, stream>>>(pv);
}

// Round 7
// 209.559 us; speedup vs baseline: 3.7326x; 1.0305x over previous
//
#include <hip/hip_runtime.h>
#include <math.h>

typedef unsigned short u16;
typedef unsigned int u32;
typedef __attribute__((ext_vector_type(8))) short short8;
typedef __attribute__((ext_vector_type(4))) float f32x4;

__device__ __forceinline__ u16 f2bf(float f) {
    u32 u = __float_as_uint(f);
    u = (u + 0x7FFFu + ((u >> 16) & 1u)) >> 16;   // RNE
    return (u16)u;
}
__device__ __forceinline__ float bf2f(u16 h) {
    return __uint_as_float(((u32)h) << 16);
}

// ============ conversion kernels ============

// fp32 -> bf16: text, html, edgeemb(64x384), posemb(13x384)
__global__ __launch_bounds__(256)
void cvt4(const float4* __restrict__ a, int na4,
          const float4* __restrict__ b, int nb4,
          const float4* __restrict__ c, int nc4,
          const float4* __restrict__ d, int nd4,
          u16* __restrict__ oa, u16* __restrict__ ob,
          u16* __restrict__ oc, u16* __restrict__ od)
{
    int idx = blockIdx.x * 256 + threadIdx.x;
    const int tot = na4 + nb4 + nc4 + nd4;
    for (; idx < tot; idx += gridDim.x * 256) {
        float4 v; u16* o;
        int t = idx;
        if (t < na4)      { v = a[t]; o = oa + (long)t * 4; }
        else if ((t -= na4) < nb4) { v = b[t]; o = ob + (long)t * 4; }
        else if ((t -= nb4) < nc4) { v = c[t]; o = oc + (long)t * 4; }
        else { t -= nc4;    v = d[t]; o = od + (long)t * 4; }
        u32 lo = (u32)f2bf(v.x) | ((u32)f2bf(v.y) << 16);
        u32 hi = (u32)f2bf(v.z) | ((u32)f2bf(v.w) << 16);
        uint2 pk; pk.x = lo; pk.y = hi;
        *reinterpret_cast<uint2*>(o) = pk;
    }
}

struct WP { const float* p[10]; };
struct WD { u16* d[10]; };

// W [384][384] fp32 -> W^T bf16 at per-weight destination
__global__ __launch_bounds__(1024)
void wtrans(WP w, WD wd)
{
    __shared__ float t[32][33];
    const int z = blockIdx.z;
    const float* W = w.p[z];
    const int k = blockIdx.x * 32 + threadIdx.y;   // row of W
    const int n = blockIdx.y * 32 + threadIdx.x;   // col of W
    t[threadIdx.y][threadIdx.x] = W[k * 384 + n];
    __syncthreads();
    const int no = blockIdx.y * 32 + threadIdx.y;
    const int ko = blockIdx.x * 32 + threadIdx.x;
    wd.d[z][no * 384 + ko] = f2bf(t[threadIdx.x][threadIdx.y]);
}

// ============ 128x128 MFMA NT core (r4-verified m97 structure) ============
// 128x128 C-tile of A[128 rows, lda] . B[128 rows, ldb]^T over K (K%32==0).
// Single-buffered [128][32] bf16 LDS per matrix, global_load_lds width 16,
// 4 waves (2x2 of 64x64), 16 MFMA per K-step.
__device__ __forceinline__ void mfma_core128(
    const u16* __restrict__ A, int lda,
    const u16* __restrict__ B, int ldb, int K,
    u16* __restrict__ As, u16* __restrict__ Bs,
    f32x4 (&acc)[4][4])
{
    const int tid  = threadIdx.x;
    const int wid  = tid >> 6;
    const int lane = tid & 63;
    const int wr = wid >> 1, wc = wid & 1;
    const int lane15 = lane & 15;
    const int kg = (lane >> 4) * 8;          // k offset of this lane's fragment
    const int srow = lane >> 2;              // staging row within 16-row group
    const int scol = (lane & 3) * 8;         // staging col (8 bf16 = 16B)

    #pragma unroll
    for (int i = 0; i < 4; ++i)
        #pragma unroll
        for (int j = 0; j < 4; ++j)
            acc[i][j] = (f32x4){0.f, 0.f, 0.f, 0.f};

    for (int k0 = 0; k0 < K; k0 += 32) {
        #pragma unroll
        for (int i = 0; i < 2; ++i) {
            const int rg = (wid * 2 + i) * 16;
            const u16* ga = A + (long)(rg + srow) * lda + (k0 + scol);
            const u16* gb = B + (long)(rg + srow) * ldb + (k0 + scol);
            u16* la = As + (wid * 2 + i) * 512;   // wave-uniform base
            u16* lb = Bs + (wid * 2 + i) * 512;
            __builtin_amdgcn_global_load_lds(
                (const __attribute__((address_space(1))) void*)ga,
                (__attribute__((address_space(3))) void*)la, 16, 0, 0);
            __builtin_amdgcn_global_load_lds(
                (const __attribute__((address_space(1))) void*)gb,
                (__attribute__((address_space(3))) void*)lb, 16, 0, 0);
        }
        __syncthreads();   // drains vmcnt -> tiles visible

        short8 af[4], bf[4];
        #pragma unroll
        for (int mi = 0; mi < 4; ++mi)
            af[mi] = *reinterpret_cast<const short8*>(
                As + (wr * 64 + mi * 16 + lane15) * 32 + kg);
        #pragma unroll
        for (int ni = 0; ni < 4; ++ni)
            bf[ni] = *reinterpret_cast<const short8*>(
                Bs + (wc * 64 + ni * 16 + lane15) * 32 + kg);
        #pragma unroll
        for (int mi = 0; mi < 4; ++mi)
            #pragma unroll
            for (int ni = 0; ni < 4; ++ni)
                acc[mi][ni] = __builtin_amdgcn_mfma_f32_16x16x32_bf16(
                    af[mi], bf[ni], acc[mi][ni], 0, 0, 0);
        __syncthreads();   // LDS reuse next iteration
    }
}

// ============ grouped f32-output GEMM (scores + bias tables / PV) ============
struct Seg {
    const u16* A; const u16* B; float* C;
    long sA, sB, sC;
    int lda, ldb, ldc, K, nbx, nbxSh, start, pad;
};
struct Segs { Seg s[6]; };

template<int NSEG>
__global__ __launch_bounds__(256)
void gemm_grouped(Segs d)
{
    __shared__ __align__(16) u16 As[4096];
    __shared__ __align__(16) u16 Bs[4096];
    const int bid = blockIdx.x;
    Seg sg = d.s[0];                         // static-index selects only
    if (NSEG > 1 && bid >= d.s[1].start) sg = d.s[1];
    if (NSEG > 2 && bid >= d.s[2].start) sg = d.s[2];
    if (NSEG > 3 && bid >= d.s[3].start) sg = d.s[3];
    if (NSEG > 4 && bid >= d.s[4].start) sg = d.s[4];
    if (NSEG > 5 && bid >= d.s[5].start) sg = d.s[5];

    const int local = bid - sg.start;
    const int bx = local & (sg.nbx - 1);
    const int by = local >> sg.nbxSh;
    const int z  = blockIdx.y;
    const int m0 = bx * 128, n0 = by * 128;

    const u16* A = sg.A + (long)z * sg.sA + (long)m0 * sg.lda;
    const u16* B = sg.B + (long)z * sg.sB + (long)n0 * sg.ldb;

    f32x4 acc[4][4];
    mfma_core128(A, sg.lda, B, sg.ldb, sg.K, As, Bs, acc);

    const int tid = threadIdx.x;
    const int wid = tid >> 6, lane = tid & 63;
    const int wr = wid >> 1, wc = wid & 1;
    const int lane15 = lane & 15;
    const int r0 = (lane >> 4) * 4;

    // C/D frag: col = lane&15, row = (lane>>4)*4 + reg  [m89]
    float* C = sg.C + (long)z * sg.sC;
    #pragma unroll
    for (int mi = 0; mi < 4; ++mi)
        #pragma unroll
        for (int r = 0; r < 4; ++r) {
            const int row = m0 + wr * 64 + mi * 16 + r0 + r;
            float* crow = C + (long)row * sg.ldc + n0 + wc * 64 + lane15;
            #pragma unroll
            for (int ni = 0; ni < 4; ++ni)
                crow[ni * 16] = acc[mi][ni][r];
        }
}

// ============ grouped projection GEMM (V^T + packed QK epilogue) ============
struct PSeg {
    const u16* A; const u16* Bw; u16* QK; u16* VT;
    int lvtSh, vtOff, nbx, nbxSh, start, pad;
};
struct PSegs { PSeg s[2]; };

__global__ __launch_bounds__(256)
void proj_grouped(PSegs d)
{
    __shared__ __align__(16) u16 As[4096];
    __shared__ __align__(16) u16 Bs[4096];
    const int bid = blockIdx.x;
    PSeg sg = d.s[0];
    if (bid >= d.s[1].start) sg = d.s[1];

    const int local = bid - sg.start;
    const int bx = local & (sg.nbx - 1);
    const int by = local >> sg.nbxSh;
    const int m0 = bx * 128, n0 = by * 128;

    const u16* A = sg.A + (long)m0 * 384;
    const u16* B = sg.Bw + (long)n0 * 384;

    f32x4 acc[4][4];
    mfma_core128(A, 384, B, 384, 384, As, Bs, acc);

    const int tid = threadIdx.x;
    const int wid = tid >> 6, lane = tid & 63;
    const int wr = wid >> 1, wc = wid & 1;
    const int lane15 = lane & 15;
    const int r0 = (lane >> 4) * 4;
    const int lmask = (1 << sg.lvtSh) - 1;

    if (n0 < 384) {
        // V columns -> stacked transposed bf16: VT[(bz*384+col)*1536 + vtOff + l]
        #pragma unroll
        for (int mi = 0; mi < 4; ++mi) {
            const int row = m0 + wr * 64 + mi * 16 + r0;
            const int bz = row >> sg.lvtSh;
            const int l  = row & lmask;
            #pragma unroll
            for (int ni = 0; ni < 4; ++ni) {
                const int col = n0 + wc * 64 + ni * 16 + lane15;
                u32 lo = (u32)f2bf(acc[mi][ni][0]) | ((u32)f2bf(acc[mi][ni][1]) << 16);
                u32 hi = (u32)f2bf(acc[mi][ni][2]) | ((u32)f2bf(acc[mi][ni][3]) << 16);
                uint2 pk; pk.x = lo; pk.y = hi;
                *reinterpret_cast<uint2*>(
                    sg.VT + ((long)bz * 384 + col) * 1536 + sg.vtOff + l) = pk;
            }
        }
    } else {
        // Q/K columns -> packed bf16 [row][1536]
        #pragma unroll
        for (int mi = 0; mi < 4; ++mi)
            #pragma unroll
            for (int r = 0; r < 4; ++r) {
                const int row = m0 + wr * 64 + mi * 16 + r0 + r;
                u16* qrow = sg.QK + (long)row * 1536 + (n0 - 384) + wc * 64 + lane15;
                #pragma unroll
                for (int ni = 0; ni < 4; ++ni)
                    qrow[ni * 16] = f2bf(acc[mi][ni][r]);
            }
    }
}

// ============ fused softmax: one block per output row, two segments ============

__device__ __forceinline__ float blockReduceMax(float v, float* red, int tid) {
    #pragma unroll
    for (int o = 32; o >= 1; o >>= 1) v = fmaxf(v, __shfl_xor(v, o));
    if ((tid & 63) == 0) red[tid >> 6] = v;
    __syncthreads();
    return fmaxf(fmaxf(red[0], red[1]), fmaxf(red[2], red[3]));
}
__device__ __forceinline__ float blockReduceSum(float v, float* red, int tid) {
    #pragma unroll
    for (int o = 32; o >= 1; o >>= 1) v += __shfl_xor(v, o);
    if ((tid & 63) == 0) red[4 + (tid >> 6)] = v;
    __syncthreads();
    return red[4] + red[5] + red[6] + red[7];
}

// blocks 0..2047: html rows (h2h cols 0-511, h2t cols 512-1535)
// blocks 2048..6143: text rows (t2h cols 0-511, t2t cols 512-1535)
__global__ __launch_bounds__(256)
void softmax_fused(const float* __restrict__ scoresH, u16* __restrict__ probsH,
                   const float* __restrict__ scoresT, u16* __restrict__ probsT,
                   const float* __restrict__ qe, const float* __restrict__ qp,
                   const int* __restrict__ H2Hmask,
                   const float* __restrict__ H2Tmask,
                   const float* __restrict__ T2Tmask, float scale)
{
    const int bid = blockIdx.x;
    const int tid = threadIdx.x;
    __shared__ float qsh[64];
    __shared__ float red[8];

    if (bid < 2048) {
        const int b = bid >> 9, i = bid & 511;
        const long rbase = ((long)b * 512 + i) * 1536;
        const float* rowS = scoresH + rbase;
        u16* rowP = probsH + rbase;
        const int*   mrow  = H2Hmask + ((long)b * 512 + i) * 512;
        const float* m2row = H2Tmask + ((long)b * 512 + i) * 1024;
        if (tid < 64) qsh[tid] = qe[((long)b * 512 + i) * 128 + tid];
        __syncthreads();

        // --- h2h (512) ---
        float x[2]; float mx = -1e30f;
        #pragma unroll
        for (int t = 0; t < 2; ++t) {
            const int j = tid + t * 256;
            const int m = mrow[j];
            float v = (rowS[j] + qsh[m]) * scale - 10000.f * (m == 0 ? 1.f : 0.f);
            x[t] = v; mx = fmaxf(mx, v);
        }
        mx = blockReduceMax(mx, red, tid);
        float s = 0.f;
        #pragma unroll
        for (int t = 0; t < 2; ++t) { x[t] = __expf(x[t] - mx); s += x[t]; }
        s = blockReduceSum(s, red, tid);
        float inv = 1.f / s;
        #pragma unroll
        for (int t = 0; t < 2; ++t) rowP[tid + t * 256] = f2bf(x[t] * inv);

        // --- h2t (1024, cols 512..1535) ---
        float y[4]; mx = -1e30f;
        #pragma unroll
        for (int t = 0; t < 4; ++t) {
            const int jj = tid + t * 256;
            float v = rowS[512 + jj] * scale - 10000.f * m2row[jj];
            y[t] = v; mx = fmaxf(mx, v);
        }
        mx = blockReduceMax(mx, red, tid);
        s = 0.f;
        #pragma unroll
        for (int t = 0; t < 4; ++t) { y[t] = __expf(y[t] - mx); s += y[t]; }
        s = blockReduceSum(s, red, tid);
        inv = 1.f / s;
        #pragma unroll
        for (int t = 0; t < 4; ++t) rowP[512 + tid + t * 256] = f2bf(y[t] * inv);
    } else {
        const int bid2 = bid - 2048;
        const int b = bid2 >> 10, i = bid2 & 1023;
        const long rbase = ((long)b * 1024 + i) * 1536;
        const float* rowS = scoresT + rbase;
        u16* rowP = probsT + rbase;
        const float* m2row = T2Tmask + ((long)b * 1024 + i) * 1024;
        if (tid < 13) qsh[tid] = qp[((long)b * 1024 + i) * 128 + tid];
        __syncthreads();

        // --- t2h (512, no mask) ---
        float x[2]; float mx = -1e30f;
        #pragma unroll
        for (int t = 0; t < 2; ++t) {
            const int j = tid + t * 256;
            float v = rowS[j] * scale;
            x[t] = v; mx = fmaxf(mx, v);
        }
        mx = blockReduceMax(mx, red, tid);
        float s = 0.f;
        #pragma unroll
        for (int t = 0; t < 2; ++t) { x[t] = __expf(x[t] - mx); s += x[t]; }
        s = blockReduceSum(s, red, tid);
        float inv = 1.f / s;
        #pragma unroll
        for (int t = 0; t < 2; ++t) rowP[tid + t * 256] = f2bf(x[t] * inv);

        // --- t2t (1024, cols 512..1535) ---
        float y[4]; mx = -1e30f;
        #pragma unroll
        for (int t = 0; t < 4; ++t) {
            const int jj = tid + t * 256;
            int pos = jj - i;
            pos = (pos < -6 ? -6 : (pos > 6 ? 6 : pos)) + 6;
            float v = (rowS[512 + jj] + qsh[pos]) * scale - 10000.f * m2row[jj];
            y[t] = v; mx = fmaxf(mx, v);
        }
        mx = blockReduceMax(mx, red, tid);
        s = 0.f;
        #pragma unroll
        for (int t = 0; t < 4; ++t) { y[t] = __expf(y[t] - mx); s += y[t]; }
        s = blockReduceSum(s, red, tid);
        inv = 1.f / s;
        #pragma unroll
        for (int t = 0; t < 4; ++t) rowP[512 + tid + t * 256] = f2bf(y[t] * inv);
    }
}

// ============ host side ============

extern "C" void kernel_launch(void* const* d_in, const int* in_sizes, int n_in,
                              void* d_out, int out_size, void* d_ws, size_t ws_size,
                              hipStream_t stream)
{
    const int Bn = 4, Lt = 1024, Lh = 512;
    const float scale = 0.05103103630798288f;  // 1/sqrt(384)

    const float* text    = (const float*)d_in[0];
    const float* html    = (const float*)d_in[1];
    const int*   H2Hmask = (const int*)  d_in[2];
    const float* T2Tmask = (const float*)d_in[3];
    const float* H2Tmask = (const float*)d_in[4];
    const float* posemb  = (const float*)d_in[6];
    const float* edgeemb = (const float*)d_in[7];
    float* out = (float*)d_out;

    // ---- workspace carve (256B-aligned) ----
    char* p = (char*)d_ws;
    auto au16 = [&](long n) { u16* r = (u16*)p;  p += ((n * 2 + 255) & ~255L); return r; };
    auto af32 = [&](long n) { float* r = (float*)p; p += ((n * 4 + 255) & ~255L); return r; };

    const long nT = (long)Bn * Lt * 384;  // 1572864
    const long nH = (long)Bn * Lh * 384;  //  786432
    u16* text_bf = au16(nT);
    u16* html_bf = au16(nH);
    u16* WTtext  = au16(5L * 384 * 384);  // [1920][384]: V_T,K_H2T,Q_T2H,Q_T2T,K_T2T
    u16* WThtml  = au16(5L * 384 * 384);  // [1920][384]: V_H,Q_H2H,K_H2H,Q_H2T,K_T2H
    u16* edge_bf = au16(128L * 384);      // rows 0-63 valid, rest pad
    u16* pos_bf  = au16(128L * 384);      // rows 0-12 valid, rest pad
    u16* textQK  = au16((long)Bn * Lt * 1536);
    u16* htmlQK  = au16((long)Bn * Lh * 1536);
    u16* VTs     = au16((long)Bn * 384 * 1536);  // [b][384][html_v^T | text_v^T]
    float* qe = af32((long)Bn * Lh * 128);       // ldc 128, cols 0-63 valid
    float* qp = af32((long)Bn * Lt * 128);       // ldc 128, cols 0-12 valid
    float* scoresH = af32((long)Bn * Lh * 1536); // [b][512][h2h(512)|h2t(1024)]
    float* scoresT = af32((long)Bn * Lt * 1536); // [b][1024][t2h(512)|t2t(1024)]
    u16* probsH = au16((long)Bn * Lh * 1536);
    u16* probsT = au16((long)Bn * Lt * 1536);

    // ---- 1-2: conversions ----
    cvt4<<<2048, 256, 0, stream>>>((const float4*)text, (int)(nT / 4),
                                   (const float4*)html, (int)(nH / 4),
                                   (const float4*)edgeemb, 64 * 384 / 4,
                                   (const float4*)posemb, 13 * 384 / 4,
                                   text_bf, html_bf, edge_bf, pos_bf);
    WP wp; WD wd;
    for (int i = 0; i < 10; ++i) wp.p[i] = (const float*)d_in[8 + i];
    const long WSZ = 147456;  // 384*384
    wd.d[0] = WTtext + 0 * WSZ;  // W_V_T
    wd.d[1] = WThtml + 0 * WSZ;  // W_V_H
    wd.d[2] = WThtml + 1 * WSZ;  // W_Q_H2H
    wd.d[3] = WThtml + 2 * WSZ;  // W_K_H2H
    wd.d[4] = WThtml + 3 * WSZ;  // W_Q_H2T
    wd.d[5] = WTtext + 1 * WSZ;  // W_K_H2T
    wd.d[6] = WTtext + 2 * WSZ;  // W_Q_T2H
    wd.d[7] = WThtml + 4 * WSZ;  // W_K_T2H
    wd.d[8] = WTtext + 3 * WSZ;  // W_Q_T2T
    wd.d[9] = WTtext + 4 * WSZ;  // W_K_T2T
    wtrans<<<dim3(12, 12, 10), dim3(32, 32), 0, stream>>>(wp, wd);

    // packed QK column offsets
    u16* h2h_q = htmlQK + 0;     u16* h2h_k = htmlQK + 384;
    u16* h2t_q = htmlQK + 768;   u16* t2h_k = htmlQK + 1152;
    u16* h2t_k = textQK + 0;     u16* t2h_q = textQK + 384;
    u16* t2t_q = textQK + 768;   u16* t2t_k = textQK + 1152;

    // ---- 3: grouped projections at 128^2 (text 32x15=480, html 16x15=240) ----
    PSegs pj;
    pj.s[0] = { text_bf, WTtext, textQK, VTs, 10, 512, 32, 5, 0,   0 };
    pj.s[1] = { html_bf, WThtml, htmlQK, VTs,  9,   0, 16, 4, 480, 0 };
    proj_grouped<<<720, 256, 0, stream>>>(pj);

    const long sQt = (long)Lt * 1536, sQh = (long)Lh * 1536;
    const long sSh = (long)Lh * 1536, sSt = (long)Lt * 1536;
    const long sV  = (long)384 * 1536;
    const long sOut = (long)(Lt + Lh) * 384;

    // ---- 4: grouped scores + bias tables (156 xy-blocks x 4 batches) ----
    Segs sc;
    sc.s[0] = { h2h_q, h2h_k,  scoresH,       sQh, sQh, sSh, 1536, 1536, 1536, 384, 4, 2,   0, 0 }; // 16
    sc.s[1] = { h2t_q, h2t_k,  scoresH + 512, sQh, sQt, sSh, 1536, 1536, 1536, 384, 4, 2,  16, 0 }; // 32
    sc.s[2] = { t2h_q, t2h_k,  scoresT,       sQt, sQh, sSt, 1536, 1536, 1536, 384, 8, 3,  48, 0 }; // 32
    sc.s[3] = { t2t_q, t2t_k,  scoresT + 512, sQt, sQt, sSt, 1536, 1536, 1536, 384, 8, 3,  80, 0 }; // 64
    sc.s[4] = { h2h_q, edge_bf, qe,           sQh, 0,   (long)Lh * 128, 1536, 384, 128, 384, 4, 2, 144, 0 }; // 4
    sc.s[5] = { t2t_q, pos_bf,  qp,           sQt, 0,   (long)Lt * 128, 1536, 384, 128, 384, 8, 3, 148, 0 }; // 8
    gemm_grouped<6><<<dim3(156, 4), 256, 0, stream>>>(sc);

    // ---- 5: fused softmax (2048 html rows + 4096 text rows) ----
    softmax_fused<<<6144, 256, 0, stream>>>(scoresH, probsH, scoresT, probsT,
                                            qe, qp, H2Hmask, H2Tmask, T2Tmask,
                                            scale);

    // ---- 6: grouped PV GEMMs at 128^2 (K=1536 stacked V) ----
    Segs pv;
    pv.s[0] = { probsH, VTs, out + (long)Lt * 384, sQh, sV, sOut, 1536, 1536, 384, 1536, 4, 2,  0, 0 }; // 12
    pv.s[1] = { probsT, VTs, out,                  sQt, sV, sOut, 1536, 1536, 384, 1536, 8, 3, 12, 0 }; // 24
    pv.s[2] = pv.s[1]; pv.s[3] = pv.s[1]; pv.s[4] = pv.s[1]; pv.s[5] = pv.s[1];
    gemm_grouped<2><<<dim3(36, 4), 256, 0, stream>>>(pv);
}